// Round 2
// baseline (26263.324 us; speedup 1.0000x reference)
//
#include <hip/hip_runtime.h>
#include <math.h>

#define SLEN 8192
#define DIM  256
#define H2N  256
#define G4   1024
#define NTAG 16
#define NEGV (-10000.0f)

// ws layout (float offsets unless noted)
#define OFF_PRE_F   0
#define OFF_PRE_B   (SLEN*G4)
#define OFF_HS_F    (2*SLEN*G4)
#define OFF_HS_B    (2*SLEN*G4 + SLEN*H2N)
#define OFF_FEATS   (2*SLEN*G4 + 2*SLEN*H2N)
#define OFF_MBOX    (OFF_FEATS + SLEN*NTAG)      // 2 dir x 2 buf x 256 u32
#define OFF_FLAGS   (OFF_MBOX + 1024)            // 2 dir x 2 buf x 32 u32 (dense!)
#define WS_NEEDED   ((size_t)(OFF_FLAGS + 128) * 4)

// ---------------- K1: pre = gather(emb, sentence[±]) @ w_ih^T + b ----------------
__global__ __launch_bounds__(256) void gemm_pre(
    const int* __restrict__ sent, const float* __restrict__ emb,
    const float* __restrict__ wf, const float* __restrict__ bf,
    const float* __restrict__ wb, const float* __restrict__ bb,
    float* __restrict__ pre_f, float* __restrict__ pre_b)
{
    const int dir = blockIdx.z;
    const float* w    = dir ? wb : wf;
    const float* bias = dir ? bb : bf;
    float* out        = dir ? pre_b : pre_f;
    const int m0 = blockIdx.x * 64, n0 = blockIdx.y * 64;

    __shared__ float As[16][68];   // [k][m], row stride 272 B (16B-aligned)
    __shared__ float Bs[16][68];   // [k][n]
    __shared__ int   sidx[64];

    const int tid = threadIdx.x;
    const int tx = tid & 15, ty = tid >> 4;

    if (tid < 64) {
        int m = m0 + tid;
        int pos = dir ? (SLEN - 1 - m) : m;
        sidx[tid] = sent[pos];
    }
    __syncthreads();

    float acc[4][4];
#pragma unroll
    for (int i = 0; i < 4; i++)
#pragma unroll
        for (int j = 0; j < 4; j++) acc[i][j] = 0.f;

    const int lr = tid >> 2, lc = (tid & 3) * 4;

    for (int k0 = 0; k0 < DIM; k0 += 16) {
        float4 av = *(const float4*)(emb + (size_t)sidx[lr] * DIM + k0 + lc);
        float4 bv = *(const float4*)(w + (size_t)(n0 + lr) * DIM + k0 + lc);
        As[lc+0][lr] = av.x; As[lc+1][lr] = av.y; As[lc+2][lr] = av.z; As[lc+3][lr] = av.w;
        Bs[lc+0][lr] = bv.x; Bs[lc+1][lr] = bv.y; Bs[lc+2][lr] = bv.z; Bs[lc+3][lr] = bv.w;
        __syncthreads();
#pragma unroll
        for (int k = 0; k < 16; k++) {
            float4 a4 = *(const float4*)&As[k][ty * 4];
            float4 b4 = *(const float4*)&Bs[k][tx * 4];
            float a[4] = {a4.x, a4.y, a4.z, a4.w};
            float b[4] = {b4.x, b4.y, b4.z, b4.w};
#pragma unroll
            for (int i = 0; i < 4; i++)
#pragma unroll
                for (int j = 0; j < 4; j++) acc[i][j] += a[i] * b[j];
        }
        __syncthreads();
    }

    float4 b4 = *(const float4*)(bias + n0 + tx*4);
#pragma unroll
    for (int i = 0; i < 4; i++) {
        float4 v;
        v.x = acc[i][0] + b4.x; v.y = acc[i][1] + b4.y;
        v.z = acc[i][2] + b4.z; v.w = acc[i][3] + b4.w;
        *(float4*)(out + (size_t)(m0 + ty*4 + i) * G4 + n0 + tx*4) = v;
    }
}

__device__ __forceinline__ float fast_sigmoid(float x) {
    return 1.f / (1.f + __expf(-x));
}
__device__ __forceinline__ float fast_tanh(float x) {
    float xc = fminf(fmaxf(x, -15.f), 15.f);
    float e = __expf(2.f * xc);
    return (e - 1.f) / (e + 1.f);
}

// ---------------- K2: bi-dir LSTM, dir = wave, flags + W-in-registers ----------------
// R9 analysis (from R8 counters): FETCH collapsed 248->42MB (co-location
// worked) but dur flat -> exchange is latency/contention-bound, and fusing
// both dirs onto ONE wave serialized their compute (~2000cy/pair) onto the
// critical path. Fixes:
//  (a) dir = wave id (128-thread block, 2 independent waves, disjoint LDS,
//      no barriers) -> the two chains' compute/waits overlap on 2 SIMDs.
//  (b) cheap spin: dense per-worker flag array (32 dwords = 2 lines per
//      dir/parity). Phase-1 spins on flags (1 load + ballot per iter, 8x
//      fewer L2 line-requests than polling the 1KB mailbox). Phase-2 is the
//      UNCHANGED self-validating tagged 4-word read (runs ~once/step).
//      Flags carry the same 1-bit tag + parity protocol: poison 0xAA (bit0=0)
//      and prior-run leftovers (etag(8190)=etag(8191)=0) both mismatch
//      etag=1 at t=0/1. Flag arrival is a hint only; phase-2 validates every
//      word, so data-store/flag-store arrival order is irrelevant.
//  (c) W slice in 128 VGPRs (32x float4, fully unrolled constant indexing ->
//      no scratch). LDS traffic/step: 33KB -> 1KB; C ~1000 -> ~500cy.
// Skew-<=1 induction (unchanged): overwriting parity-p slots at t+2 requires
// all workers to have produced t+1, which requires all observed t.
__global__ __launch_bounds__(128) void lstm_kernel(
    const float* __restrict__ pre_f, const float* __restrict__ pre_b,
    const float* __restrict__ whh_f, const float* __restrict__ whh_b,
    const float* __restrict__ h0_f, const float* __restrict__ c0_f,
    const float* __restrict__ h0_b, const float* __restrict__ c0_b,
    float* __restrict__ hs_f, float* __restrict__ hs_b,
    unsigned* __restrict__ mbox, unsigned* __restrict__ flags)
{
    if (blockIdx.x & 7) return;          // XCD co-location: keep b%8==0 only
    const int cb = blockIdx.x >> 3;      // worker id 0..31
    const int d  = threadIdx.x >> 6;     // direction = wave id
    const int l  = threadIdx.x & 63;     // lane
    const int cell0 = cb * 8;

    const float* pre = d ? pre_b : pre_f;
    const float* whh = d ? whh_b : whh_f;
    const float* h0  = d ? h0_b  : h0_f;
    const float* c0  = d ? c0_b  : c0_f;
    unsigned* hist   = (unsigned*)(d ? hs_b : hs_f);
    unsigned* mb_dir = mbox  + d * 512;
    unsigned* fl_dir = flags + d * 64;

    const int r = l >> 1;                // local row 0..31 (gate-major)
    const int half = l & 1;              // k-half: [half*128, half*128+128)
    const int g = r >> 3, cl = r & 7;
    const int grow = g * 256 + cell0 + cl;   // global gate row (0..1023)
    const int ai = l & 7;                // activation cell index (lanes 0..7)

    __shared__ __align__(16) float h_lds[2][256];   // per-dir, disjoint

    // W slice -> registers: 32 x float4 = 128 VGPRs, constant-indexed only
    float4 wreg[32];
    {
        const float* wsrc = whh + (size_t)grow * H2N + half * 128;
#pragma unroll
        for (int j = 0; j < 32; j++) wreg[j] = *(const float4*)(wsrc + 4 * j);
    }
    ((float4*)h_lds[d])[l] = ((const float4*)h0)[l];
    float c = (l < 8) ? c0[cell0 + l] : 0.f;
    // no cross-wave LDS sharing: intra-wave program order suffices, no barrier

    const float* pre_base = pre + grow;
    float pre_cur = (half == 0) ? pre_base[0] : 0.f;

    // one LSTM step producing h_T: dot(W,h) from regs x LDS-broadcast,
    // activations on lanes 0..7, tagged store + flag + history.
#define LSTM_STEP(T, PRE)                                                      \
    {                                                                          \
        const unsigned etag_ = ((((unsigned)(T)) >> 1) & 1u) ^ 1u;             \
        unsigned* mb_ = mb_dir + ((T) & 1) * 256;                              \
        unsigned* fl_ = fl_dir + ((T) & 1) * 32;                               \
        float a0 = (PRE), a1 = 0.f, a2 = 0.f, a3 = 0.f;                        \
        const float4* hr_ = (const float4*)(h_lds[d] + half * 128);            \
_Pragma("unroll")                                                              \
        for (int j = 0; j < 32; j++) {                                         \
            float4 hv = hr_[j];                                                \
            a0 += wreg[j].x * hv.x; a1 += wreg[j].y * hv.y;                    \
            a2 += wreg[j].z * hv.z; a3 += wreg[j].w * hv.w;                    \
        }                                                                      \
        float sum = (a0 + a1) + (a2 + a3);                                     \
        sum += __shfl_xor(sum, 1, 64);                                         \
        float s_i = __shfl(sum,      2 * ai, 64);                              \
        float s_f = __shfl(sum, 16 + 2 * ai, 64);                              \
        float s_g = __shfl(sum, 32 + 2 * ai, 64);                              \
        float s_o = __shfl(sum, 48 + 2 * ai, 64);                              \
        if (l < 8) {                                                           \
            float i_ = fast_sigmoid(s_i);                                      \
            float f_ = fast_sigmoid(s_f);                                      \
            float g_ = fast_tanh(s_g);                                         \
            float o_ = fast_sigmoid(s_o);                                      \
            c = f_ * c + i_ * g_;                                              \
            float h = o_ * fast_tanh(c);                                       \
            unsigned hm = (__float_as_uint(h) & ~1u) | etag_;                  \
            __hip_atomic_store(mb_ + cell0 + l, hm,                            \
                               __ATOMIC_RELAXED, __HIP_MEMORY_SCOPE_AGENT);    \
            if (l == 0)                                                        \
                __hip_atomic_store(fl_ + cb, etag_,                            \
                                   __ATOMIC_RELAXED, __HIP_MEMORY_SCOPE_AGENT);\
            __builtin_nontemporal_store(hm,                                    \
                hist + (size_t)(T) * H2N + cell0 + l);                         \
        }                                                                      \
    }

    // poll step T: phase-1 cheap flag spin (2 lines), phase-2 validated read
#define POLL(T)                                                                \
    {                                                                          \
        const unsigned etag_ = ((((unsigned)(T)) >> 1) & 1u) ^ 1u;             \
        const unsigned* fl_ = fl_dir + ((T) & 1) * 32;                         \
        int spin_ = 0; unsigned fv_;                                           \
        do {                                                                   \
            fv_ = __hip_atomic_load(fl_ + (l & 31),                            \
                                    __ATOMIC_RELAXED, __HIP_MEMORY_SCOPE_AGENT); \
        } while (__ballot(((fv_ ^ etag_) & 1u) == 0u) != ~0ull                 \
                 && ++spin_ < 4000000);                                        \
        const unsigned* ms_ = mb_dir + ((T) & 1) * 256 + 4 * l;                \
        unsigned v0, v1, v2, v3; spin_ = 0;                                    \
        do {                                                                   \
            v0 = __hip_atomic_load(ms_ + 0, __ATOMIC_RELAXED, __HIP_MEMORY_SCOPE_AGENT); \
            v1 = __hip_atomic_load(ms_ + 1, __ATOMIC_RELAXED, __HIP_MEMORY_SCOPE_AGENT); \
            v2 = __hip_atomic_load(ms_ + 2, __ATOMIC_RELAXED, __HIP_MEMORY_SCOPE_AGENT); \
            v3 = __hip_atomic_load(ms_ + 3, __ATOMIC_RELAXED, __HIP_MEMORY_SCOPE_AGENT); \
        } while ((((v0 ^ etag_) | (v1 ^ etag_) | (v2 ^ etag_) | (v3 ^ etag_)) & 1u) \
                 && ++spin_ < 2000000);                                        \
        float4 hv_;                                                            \
        hv_.x = __uint_as_float(v0); hv_.y = __uint_as_float(v1);              \
        hv_.z = __uint_as_float(v2); hv_.w = __uint_as_float(v3);              \
        *(float4*)(h_lds[d] + 4 * l) = hv_;                                    \
    }

    // prologue: produce h_0
    LSTM_STEP(0, pre_cur);

    for (int t = 0; t < SLEN - 1; t++) {
        // issue pre(t+1) load first: resolves under the flag spin
        float pn = (half == 0) ? pre_base[(size_t)(t + 1) * G4] : 0.f;
        POLL(t);
        LSTM_STEP(t + 1, pn);
    }
#undef LSTM_STEP
#undef POLL
}

// ---------------- K3: feats = concat(hs_f[s], hs_b[S-1-s]) @ w_out^T + b_out ----------------
__global__ __launch_bounds__(256) void feats_kernel(
    const float* __restrict__ hs_f, const float* __restrict__ hs_b,
    const float* __restrict__ w_out, const float* __restrict__ b_out,
    float* __restrict__ feats)
{
    const int rs0 = blockIdx.x * 16;
    const int tid = threadIdx.x;
    const int r = tid >> 4, cc = tid & 15;

    __shared__ float Hs[16][516];   // row stride 2064 B (16B-aligned)
    for (int i = tid; i < 16 * 256; i += 256) {
        int rr = i >> 8, k = i & 255;
        Hs[rr][k]       = hs_f[(size_t)(rs0 + rr) * H2N + k];
        Hs[rr][256 + k] = hs_b[(size_t)(SLEN - 1 - (rs0 + rr)) * H2N + k];
    }
    __syncthreads();

    float acc = 0.f;
    const float* wr = w_out + (size_t)cc * 512;
    const float* hrow = Hs[r];
#pragma unroll 4
    for (int kq = 0; kq < 128; kq++) {
        float4 hv = *(const float4*)(hrow + 4 * kq);
        float4 wv = *(const float4*)(wr + 4 * kq);
        acc += hv.x * wv.x; acc += hv.y * wv.y;
        acc += hv.z * wv.z; acc += hv.w * wv.w;
    }
    feats[(size_t)(rs0 + r) * NTAG + cc] = acc + b_out[cc];
}

// ---------------- K4: Viterbi scan + backtrack (single wave, LDS back-ptrs) ----------------
__global__ __launch_bounds__(64) void viterbi_kernel(
    const float* __restrict__ feats, const float* __restrict__ trans,
    float* __restrict__ out)
{
    __shared__ unsigned char back_s[SLEN * 8];   // 65536 B, [t][tag/2] nibbles

    const int lane = threadIdx.x;
    const int nx = lane >> 2, pc = lane & 3;   // next tag, prev-chunk

    float tr[4];
#pragma unroll
    for (int j = 0; j < 4; j++) tr[j] = trans[nx * NTAG + pc * 4 + j];

    // score of tag g lives (replicated) in lanes 4g..4g+3
    float sc = (nx == 0) ? 0.f : NEGV;
    float fe = feats[nx];   // prefetch t=0

    for (int t = 0; t < SLEN; t++) {
        float fe_next = (t < SLEN - 1) ? feats[(size_t)(t + 1) * NTAG + nx] : 0.f;

        float bv; int bi;
#pragma unroll
        for (int j = 0; j < 4; j++) {
            float s = __shfl(sc, 4 * (pc * 4 + j), 64);
            float cand = s + tr[j];
            if (j == 0) { bv = cand; bi = pc * 4; }
            else if (cand > bv) { bv = cand; bi = pc * 4 + j; }
        }
        // combine across the 4 prev-chunks; first-max semantics (tie -> smaller idx)
#pragma unroll
        for (int off = 1; off < 4; off <<= 1) {
            float ov = __shfl_xor(bv, off, 64);
            int   oi = __shfl_xor(bi, off, 64);
            if (ov > bv || (ov == bv && oi < bi)) { bv = ov; bi = oi; }
        }
        // nibble-pack: lane (nx even, pc==0) stores [bi(nx) | bi(nx+1)<<4]
        int bi_part = __shfl(bi, (nx | 1) * 4, 64);
        if (pc == 0 && (nx & 1) == 0)
            back_s[t * 8 + (nx >> 1)] = (unsigned char)((bi & 15) | (bi_part << 4));
        sc = bv + fe;
        fe = fe_next;
    }

    // final = last + trans[END=1]; first-argmax
    float bestv = 0.f; int besti = 0;
#pragma unroll
    for (int j = 0; j < NTAG; j++) {
        float sj = __shfl(sc, 4 * j, 64);
        float fj = sj + trans[1 * NTAG + j];
        if (j == 0) { bestv = fj; besti = 0; }
        else if (fj > bestv) { bestv = fj; besti = j; }
    }
    __syncthreads();

    if (lane == 0) {
        out[0] = bestv;
        int cur = besti;
        for (int t = SLEN - 1; t >= 1; t--) {
            out[1 + t] = (float)cur;
            unsigned char byte = back_s[t * 8 + (cur >> 1)];
            cur = (cur & 1) ? (byte >> 4) : (byte & 15);
        }
        out[1] = (float)cur;
    }
}

extern "C" void kernel_launch(void* const* d_in, const int* in_sizes, int n_in,
                              void* d_out, int out_size, void* d_ws, size_t ws_size,
                              hipStream_t stream) {
    const int*   sent   = (const int*)d_in[0];
    const float* emb    = (const float*)d_in[1];
    const float* w_ih_f = (const float*)d_in[2];
    const float* w_hh_f = (const float*)d_in[3];
    const float* b_f    = (const float*)d_in[4];
    const float* w_ih_b = (const float*)d_in[5];
    const float* w_hh_b = (const float*)d_in[6];
    const float* b_b    = (const float*)d_in[7];
    const float* h0_f   = (const float*)d_in[8];
    const float* c0_f   = (const float*)d_in[9];
    const float* h0_b   = (const float*)d_in[10];
    const float* c0_b   = (const float*)d_in[11];
    const float* w_out  = (const float*)d_in[12];
    const float* b_out  = (const float*)d_in[13];
    const float* trans  = (const float*)d_in[14];
    float* out = (float*)d_out;

    if (ws_size < WS_NEEDED) return;  // visible failure, no OOB writes

    float* ws = (float*)d_ws;
    float* pre_f = ws + OFF_PRE_F;
    float* pre_b = ws + OFF_PRE_B;
    float* hs_f  = ws + OFF_HS_F;
    float* hs_b  = ws + OFF_HS_B;
    float* feats = ws + OFF_FEATS;
    unsigned* mbox  = (unsigned*)(ws + OFF_MBOX);
    unsigned* flags = (unsigned*)(ws + OFF_FLAGS);

    gemm_pre<<<dim3(128, 16, 2), 256, 0, stream>>>(sent, emb, w_ih_f, b_f, w_ih_b, b_b, pre_f, pre_b);
    lstm_kernel<<<256, 128, 0, stream>>>(pre_f, pre_b, w_hh_f, w_hh_b,
                                         h0_f, c0_f, h0_b, c0_b, hs_f, hs_b, mbox, flags);
    feats_kernel<<<512, 256, 0, stream>>>(hs_f, hs_b, w_out, b_out, feats);
    viterbi_kernel<<<1, 64, 0, stream>>>(feats, trans, out);
}

// Round 3
// 22158.293 us; speedup vs baseline: 1.1853x; 1.1853x over previous
//
#include <hip/hip_runtime.h>
#include <math.h>

#define SLEN 8192
#define DIM  256
#define H2N  256
#define G4   1024
#define NTAG 16
#define NEGV (-10000.0f)

// ws layout (float offsets unless noted)
#define OFF_PRE_F   0
#define OFF_PRE_B   (SLEN*G4)
#define OFF_HS_F    (2*SLEN*G4)
#define OFF_HS_B    (2*SLEN*G4 + SLEN*H2N)
#define OFF_FEATS   (2*SLEN*G4 + 2*SLEN*H2N)
#define OFF_MBOX    (OFF_FEATS + SLEN*NTAG)      // 2 dir x 2 buf x 256 u32
#define WS_NEEDED   ((size_t)(OFF_MBOX + 1024) * 4)

typedef unsigned int u32x4 __attribute__((ext_vector_type(4)));

// ---------------- K1: pre = gather(emb, sentence[±]) @ w_ih^T + b ----------------
__global__ __launch_bounds__(256) void gemm_pre(
    const int* __restrict__ sent, const float* __restrict__ emb,
    const float* __restrict__ wf, const float* __restrict__ bf,
    const float* __restrict__ wb, const float* __restrict__ bb,
    float* __restrict__ pre_f, float* __restrict__ pre_b)
{
    const int dir = blockIdx.z;
    const float* w    = dir ? wb : wf;
    const float* bias = dir ? bb : bf;
    float* out        = dir ? pre_b : pre_f;
    const int m0 = blockIdx.x * 64, n0 = blockIdx.y * 64;

    __shared__ float As[16][68];   // [k][m], row stride 272 B (16B-aligned)
    __shared__ float Bs[16][68];   // [k][n]
    __shared__ int   sidx[64];

    const int tid = threadIdx.x;
    const int tx = tid & 15, ty = tid >> 4;

    if (tid < 64) {
        int m = m0 + tid;
        int pos = dir ? (SLEN - 1 - m) : m;
        sidx[tid] = sent[pos];
    }
    __syncthreads();

    float acc[4][4];
#pragma unroll
    for (int i = 0; i < 4; i++)
#pragma unroll
        for (int j = 0; j < 4; j++) acc[i][j] = 0.f;

    const int lr = tid >> 2, lc = (tid & 3) * 4;

    for (int k0 = 0; k0 < DIM; k0 += 16) {
        float4 av = *(const float4*)(emb + (size_t)sidx[lr] * DIM + k0 + lc);
        float4 bv = *(const float4*)(w + (size_t)(n0 + lr) * DIM + k0 + lc);
        As[lc+0][lr] = av.x; As[lc+1][lr] = av.y; As[lc+2][lr] = av.z; As[lc+3][lr] = av.w;
        Bs[lc+0][lr] = bv.x; Bs[lc+1][lr] = bv.y; Bs[lc+2][lr] = bv.z; Bs[lc+3][lr] = bv.w;
        __syncthreads();
#pragma unroll
        for (int k = 0; k < 16; k++) {
            float4 a4 = *(const float4*)&As[k][ty * 4];
            float4 b4 = *(const float4*)&Bs[k][tx * 4];
            float a[4] = {a4.x, a4.y, a4.z, a4.w};
            float b[4] = {b4.x, b4.y, b4.z, b4.w};
#pragma unroll
            for (int i = 0; i < 4; i++)
#pragma unroll
                for (int j = 0; j < 4; j++) acc[i][j] += a[i] * b[j];
        }
        __syncthreads();
    }

    float4 b4 = *(const float4*)(bias + n0 + tx*4);
#pragma unroll
    for (int i = 0; i < 4; i++) {
        float4 v;
        v.x = acc[i][0] + b4.x; v.y = acc[i][1] + b4.y;
        v.z = acc[i][2] + b4.z; v.w = acc[i][3] + b4.w;
        *(float4*)(out + (size_t)(m0 + ty*4 + i) * G4 + n0 + tx*4) = v;
    }
}

__device__ __forceinline__ float fast_sigmoid(float x) {
    return 1.f / (1.f + __expf(-x));
}
__device__ __forceinline__ float fast_tanh(float x) {
    float xc = fminf(fmaxf(x, -15.f), 15.f);
    float e = __expf(2.f * xc);
    return (e - 1.f) / (e + 1.f);
}

// ---------------- K2: two LSTMs, 32 workers/dir, de-flooded mailbox sync ----------------
// R10 analysis: R1 proved agent-scope exchange is NOT served by the local XCD
// L2 (co-location collapsed FETCH 248->42MB, latency flat) -> coherence point
// is fabric/LLC, RT ~700-900cy placement-independent. R2 proved the compiler
// demotes big W register arrays under spin loops (VGPR 88) -> W stays in LDS
// (proven R0 form, VGPR 132). Remaining suspect for the ~2000cy gap between
// RT-chain (~3500cy) and measured period (~5500cy): POLL FLOODING -- 64 waves
// x 4 separate dword atomic loads continuously in flight queue the coherence
// point and delay the producers' own store commits. This round:
//  (a) spin iteration = ONE global_load_dwordx4 sc0 sc1 (L1/L2 bypass, reads
//      at the coherence point; same visibility class as the atomic loads it
//      replaces) -> 4x fewer requests;
//  (b) s_sleep(1) backoff after each failed check (fast-path first check)
//      -> ~5-10x lower poll issue rate, <=64cy added detection quantization;
//  (c) dir-per-XCD placement: keep (b&7)<2, d=b&1 -> dir0 workers on XCD0,
//      dir1 on XCD1 (splits pre/W/hist streaming; mailbox RT unchanged).
// Protocol unchanged: 2-buffer parity ping-pong, 1-bit tag in mantissa LSB
// (<=1 ulp), each dword self-validating. Poison 0xAA (bit0=0) and stale
// tags (etag(8190/8191)=0) mismatch etag=1 at t=0/1 -> no false positive.
// Skew<=1 induction: overwriting parity-p at t+2 requires all produced t+1,
// which requires all observed t.
__global__ __launch_bounds__(64) void lstm_kernel(
    const float* __restrict__ pre_f, const float* __restrict__ pre_b,
    const float* __restrict__ whh_f, const float* __restrict__ whh_b,
    const float* __restrict__ h0_f, const float* __restrict__ c0_f,
    const float* __restrict__ h0_b, const float* __restrict__ c0_b,
    float* __restrict__ hs_f, float* __restrict__ hs_b,
    unsigned* __restrict__ mbox)
{
    if ((blockIdx.x & 7) > 1) return;      // keep 64 of 256 blocks
    const int d  = blockIdx.x & 1;         // direction -> XCD d (heuristic)
    const int cb = blockIdx.x >> 3;        // worker id 0..31
    const int cell0 = cb * 8;

    const float* pre = d ? pre_b : pre_f;
    const float* whh = d ? whh_b : whh_f;
    const float* h0  = d ? h0_b : h0_f;
    const float* c0  = d ? c0_b : c0_f;
    float* hs        = d ? hs_b : hs_f;

    const int l = threadIdx.x;       // 0..63
    const int r = l >> 1;            // local row 0..31 (gate-major)
    const int half = l & 1;          // k-half: [half*128, half*128+128)
    const int g = r >> 3, cl = r & 7;
    const int grow = g * 256 + cell0 + cl;   // global gate row (0..1023)

    __shared__ __align__(16) float4 w_pack4[32 * 64];   // 32 KB, [j][lane]
    __shared__ __align__(16) float  h_lds[256];

    // stage W into packed LDS (coalesced global reads, conflict-free reads)
    {
        const float4* src = (const float4*)(whh + (size_t)grow * H2N + half * 128);
#pragma unroll
        for (int j = 0; j < 32; j++) w_pack4[j * 64 + l] = src[j];
    }
    ((float4*)h_lds)[l] = ((const float4*)h0)[l];
    float c = (l < 8) ? c0[cell0 + l] : 0.f;
    __syncthreads();

    const float* pre_base = pre + grow;
    float pre_cur = (half == 0) ? pre_base[0] : 0.f;
    const int ai = l & 7;            // activation cell index (lanes 0..7)
    unsigned* mb_dir = mbox + d * 512;

    for (int t = 0; t < SLEN; t++) {
        float pre_next = (half == 0 && t < SLEN - 1) ? pre_base[(size_t)(t + 1) * G4] : 0.f;
        const unsigned etag = (((unsigned)t >> 1) & 1u) ^ 1u;
        unsigned* mb = mb_dir + (t & 1) * 256;

        // dot over this thread's k-half: w + h from LDS (conflict-free)
        float a0 = pre_cur, a1 = 0.f, a2 = 0.f, a3 = 0.f;
        const float4* hrow4 = (const float4*)(h_lds + half * 128);
#pragma unroll
        for (int j = 0; j < 32; j++) {
            float4 wv = w_pack4[j * 64 + l];
            float4 hv = hrow4[j];
            a0 += wv.x * hv.x; a1 += wv.y * hv.y;
            a2 += wv.z * hv.z; a3 += wv.w * hv.w;
        }
        float sum = (a0 + a1) + (a2 + a3);
        sum += __shfl_xor(sum, 1, 64);   // row r total at lanes 2r, 2r+1

        // gate sums for cell ai: rows ai, 8+ai, 16+ai, 24+ai
        float s_i = __shfl(sum, 2 * ai, 64);
        float s_f = __shfl(sum, 16 + 2 * ai, 64);
        float s_g = __shfl(sum, 32 + 2 * ai, 64);
        float s_o = __shfl(sum, 48 + 2 * ai, 64);

        if (l < 8) {
            float i_ = fast_sigmoid(s_i);
            float f_ = fast_sigmoid(s_f);
            float g_ = fast_tanh(s_g);
            float o_ = fast_sigmoid(s_o);
            c = f_ * c + i_ * g_;
            float h = o_ * fast_tanh(c);
            unsigned hm = (__float_as_uint(h) & ~1u) | etag;   // tag bit, <=1 ulp
            __hip_atomic_store(mb + cell0 + l, hm,
                               __ATOMIC_RELAXED, __HIP_MEMORY_SCOPE_AGENT);
            // history for feats: off critical path, nontemporal
            __builtin_nontemporal_store(hm, (unsigned*)hs + (size_t)t * H2N + cell0 + l);
        }

        // poll: ONE dwordx4 (cells 4l..4l+3) per iteration, backoff on miss.
        // sc0 sc1 = bypass L1/L2, read at the coherence point (where the
        // agent-scope stores land). vmcnt(0) inside also drains pre_next.
        const unsigned* ms4 = mb + 4 * l;
        u32x4 v;
        int spin = 0;
        for (;;) {
            asm volatile("global_load_dwordx4 %0, %1, off sc0 sc1\n\t"
                         "s_waitcnt vmcnt(0)"
                         : "=v"(v) : "v"(ms4) : "memory");
            if (!(((v.x ^ etag) | (v.y ^ etag) | (v.z ^ etag) | (v.w ^ etag)) & 1u))
                break;
            if (++spin >= 300000) break;   // deadlock guard only
            __builtin_amdgcn_s_sleep(1);   // ~64cy backoff: de-flood the LLC
        }

        float4 hv4;
        hv4.x = __uint_as_float(v.x); hv4.y = __uint_as_float(v.y);
        hv4.z = __uint_as_float(v.z); hv4.w = __uint_as_float(v.w);
        *(float4*)(h_lds + 4 * l) = hv4;
        __syncthreads();             // single wave: lgkm drain + barrier
        pre_cur = pre_next;
    }
}

// ---------------- K3: feats = concat(hs_f[s], hs_b[S-1-s]) @ w_out^T + b_out ----------------
__global__ __launch_bounds__(256) void feats_kernel(
    const float* __restrict__ hs_f, const float* __restrict__ hs_b,
    const float* __restrict__ w_out, const float* __restrict__ b_out,
    float* __restrict__ feats)
{
    const int rs0 = blockIdx.x * 16;
    const int tid = threadIdx.x;
    const int r = tid >> 4, cc = tid & 15;

    __shared__ float Hs[16][516];   // row stride 2064 B (16B-aligned)
    for (int i = tid; i < 16 * 256; i += 256) {
        int rr = i >> 8, k = i & 255;
        Hs[rr][k]       = hs_f[(size_t)(rs0 + rr) * H2N + k];
        Hs[rr][256 + k] = hs_b[(size_t)(SLEN - 1 - (rs0 + rr)) * H2N + k];
    }
    __syncthreads();

    float acc = 0.f;
    const float* wr = w_out + (size_t)cc * 512;
    const float* hrow = Hs[r];
#pragma unroll 4
    for (int kq = 0; kq < 128; kq++) {
        float4 hv = *(const float4*)(hrow + 4 * kq);
        float4 wv = *(const float4*)(wr + 4 * kq);
        acc += hv.x * wv.x; acc += hv.y * wv.y;
        acc += hv.z * wv.z; acc += hv.w * wv.w;
    }
    feats[(size_t)(rs0 + r) * NTAG + cc] = acc + b_out[cc];
}

// ---------------- K4: Viterbi scan + backtrack (single wave, LDS back-ptrs) ----------------
__global__ __launch_bounds__(64) void viterbi_kernel(
    const float* __restrict__ feats, const float* __restrict__ trans,
    float* __restrict__ out)
{
    __shared__ unsigned char back_s[SLEN * 8];   // 65536 B, [t][tag/2] nibbles

    const int lane = threadIdx.x;
    const int nx = lane >> 2, pc = lane & 3;   // next tag, prev-chunk

    float tr[4];
#pragma unroll
    for (int j = 0; j < 4; j++) tr[j] = trans[nx * NTAG + pc * 4 + j];

    // score of tag g lives (replicated) in lanes 4g..4g+3
    float sc = (nx == 0) ? 0.f : NEGV;
    float fe = feats[nx];   // prefetch t=0

    for (int t = 0; t < SLEN; t++) {
        float fe_next = (t < SLEN - 1) ? feats[(size_t)(t + 1) * NTAG + nx] : 0.f;

        float bv; int bi;
#pragma unroll
        for (int j = 0; j < 4; j++) {
            float s = __shfl(sc, 4 * (pc * 4 + j), 64);
            float cand = s + tr[j];
            if (j == 0) { bv = cand; bi = pc * 4; }
            else if (cand > bv) { bv = cand; bi = pc * 4 + j; }
        }
        // combine across the 4 prev-chunks; first-max semantics (tie -> smaller idx)
#pragma unroll
        for (int off = 1; off < 4; off <<= 1) {
            float ov = __shfl_xor(bv, off, 64);
            int   oi = __shfl_xor(bi, off, 64);
            if (ov > bv || (ov == bv && oi < bi)) { bv = ov; bi = oi; }
        }
        // nibble-pack: lane (nx even, pc==0) stores [bi(nx) | bi(nx+1)<<4]
        int bi_part = __shfl(bi, (nx | 1) * 4, 64);
        if (pc == 0 && (nx & 1) == 0)
            back_s[t * 8 + (nx >> 1)] = (unsigned char)((bi & 15) | (bi_part << 4));
        sc = bv + fe;
        fe = fe_next;
    }

    // final = last + trans[END=1]; first-argmax
    float bestv = 0.f; int besti = 0;
#pragma unroll
    for (int j = 0; j < NTAG; j++) {
        float sj = __shfl(sc, 4 * j, 64);
        float fj = sj + trans[1 * NTAG + j];
        if (j == 0) { bestv = fj; besti = 0; }
        else if (fj > bestv) { bestv = fj; besti = j; }
    }
    __syncthreads();

    if (lane == 0) {
        out[0] = bestv;
        int cur = besti;
        for (int t = SLEN - 1; t >= 1; t--) {
            out[1 + t] = (float)cur;
            unsigned char byte = back_s[t * 8 + (cur >> 1)];
            cur = (cur & 1) ? (byte >> 4) : (byte & 15);
        }
        out[1] = (float)cur;
    }
}

extern "C" void kernel_launch(void* const* d_in, const int* in_sizes, int n_in,
                              void* d_out, int out_size, void* d_ws, size_t ws_size,
                              hipStream_t stream) {
    const int*   sent   = (const int*)d_in[0];
    const float* emb    = (const float*)d_in[1];
    const float* w_ih_f = (const float*)d_in[2];
    const float* w_hh_f = (const float*)d_in[3];
    const float* b_f    = (const float*)d_in[4];
    const float* w_ih_b = (const float*)d_in[5];
    const float* w_hh_b = (const float*)d_in[6];
    const float* b_b    = (const float*)d_in[7];
    const float* h0_f   = (const float*)d_in[8];
    const float* c0_f   = (const float*)d_in[9];
    const float* h0_b   = (const float*)d_in[10];
    const float* c0_b   = (const float*)d_in[11];
    const float* w_out  = (const float*)d_in[12];
    const float* b_out  = (const float*)d_in[13];
    const float* trans  = (const float*)d_in[14];
    float* out = (float*)d_out;

    if (ws_size < WS_NEEDED) return;  // visible failure, no OOB writes

    float* ws = (float*)d_ws;
    float* pre_f = ws + OFF_PRE_F;
    float* pre_b = ws + OFF_PRE_B;
    float* hs_f  = ws + OFF_HS_F;
    float* hs_b  = ws + OFF_HS_B;
    float* feats = ws + OFF_FEATS;
    unsigned* mbox = (unsigned*)(ws + OFF_MBOX);

    gemm_pre<<<dim3(128, 16, 2), 256, 0, stream>>>(sent, emb, w_ih_f, b_f, w_ih_b, b_b, pre_f, pre_b);
    lstm_kernel<<<256, 64, 0, stream>>>(pre_f, pre_b, w_hh_f, w_hh_b,
                                        h0_f, c0_f, h0_b, c0_b, hs_f, hs_b, mbox);
    feats_kernel<<<512, 256, 0, stream>>>(hs_f, hs_b, w_out, b_out, feats);
    viterbi_kernel<<<1, 64, 0, stream>>>(feats, trans, out);
}

// Round 5
// 21314.801 us; speedup vs baseline: 1.2322x; 1.0396x over previous
//
#include <hip/hip_runtime.h>
#include <math.h>

#define SLEN 8192
#define DIM  256
#define H2N  256
#define G4   1024
#define NTAG 16
#define NEGV (-10000.0f)

// ws layout (float offsets unless noted)
#define OFF_PRE_F   0
#define OFF_PRE_B   (SLEN*G4)
#define OFF_HS_F    (2*SLEN*G4)
#define OFF_HS_B    (2*SLEN*G4 + SLEN*H2N)
#define OFF_FEATS   (2*SLEN*G4 + 2*SLEN*H2N)
#define OFF_MBOX    (OFF_FEATS + SLEN*NTAG)      // 2 dir x 2 buf x 256 u32
#define WS_NEEDED   ((size_t)(OFF_MBOX + 1024) * 4)

typedef unsigned int u32x4 __attribute__((ext_vector_type(4)));

// ---------------- K1: pre = gather(emb, sentence[±]) @ w_ih^T + b ----------------
__global__ __launch_bounds__(256) void gemm_pre(
    const int* __restrict__ sent, const float* __restrict__ emb,
    const float* __restrict__ wf, const float* __restrict__ bf,
    const float* __restrict__ wb, const float* __restrict__ bb,
    float* __restrict__ pre_f, float* __restrict__ pre_b)
{
    const int dir = blockIdx.z;
    const float* w    = dir ? wb : wf;
    const float* bias = dir ? bb : bf;
    float* out        = dir ? pre_b : pre_f;
    const int m0 = blockIdx.x * 64, n0 = blockIdx.y * 64;

    __shared__ float As[16][68];   // [k][m], row stride 272 B (16B-aligned)
    __shared__ float Bs[16][68];   // [k][n]
    __shared__ int   sidx[64];

    const int tid = threadIdx.x;
    const int tx = tid & 15, ty = tid >> 4;

    if (tid < 64) {
        int m = m0 + tid;
        int pos = dir ? (SLEN - 1 - m) : m;
        sidx[tid] = sent[pos];
    }
    __syncthreads();

    float acc[4][4];
#pragma unroll
    for (int i = 0; i < 4; i++)
#pragma unroll
        for (int j = 0; j < 4; j++) acc[i][j] = 0.f;

    const int lr = tid >> 2, lc = (tid & 3) * 4;

    for (int k0 = 0; k0 < DIM; k0 += 16) {
        float4 av = *(const float4*)(emb + (size_t)sidx[lr] * DIM + k0 + lc);
        float4 bv = *(const float4*)(w + (size_t)(n0 + lr) * DIM + k0 + lc);
        As[lc+0][lr] = av.x; As[lc+1][lr] = av.y; As[lc+2][lr] = av.z; As[lc+3][lr] = av.w;
        Bs[lc+0][lr] = bv.x; Bs[lc+1][lr] = bv.y; Bs[lc+2][lr] = bv.z; Bs[lc+3][lr] = bv.w;
        __syncthreads();
#pragma unroll
        for (int k = 0; k < 16; k++) {
            float4 a4 = *(const float4*)&As[k][ty * 4];
            float4 b4 = *(const float4*)&Bs[k][tx * 4];
            float a[4] = {a4.x, a4.y, a4.z, a4.w};
            float b[4] = {b4.x, b4.y, b4.z, b4.w};
#pragma unroll
            for (int i = 0; i < 4; i++)
#pragma unroll
                for (int j = 0; j < 4; j++) acc[i][j] += a[i] * b[j];
        }
        __syncthreads();
    }

    float4 b4 = *(const float4*)(bias + n0 + tx*4);
#pragma unroll
    for (int i = 0; i < 4; i++) {
        float4 v;
        v.x = acc[i][0] + b4.x; v.y = acc[i][1] + b4.y;
        v.z = acc[i][2] + b4.z; v.w = acc[i][3] + b4.w;
        *(float4*)(out + (size_t)(m0 + ty*4 + i) * G4 + n0 + tx*4) = v;
    }
}

__device__ __forceinline__ float fast_sigmoid(float x) {
    return 1.f / (1.f + __expf(-x));
}
__device__ __forceinline__ float fast_tanh(float x) {
    float xc = fminf(fmaxf(x, -15.f), 15.f);
    float e = __expf(2.f * xc);
    return (e - 1.f) / (e + 1.f);
}

// ---------------- K2: two LSTMs, 8 FAT workers/dir (4 waves, 32 cells each) ----------------
// R12 analysis: R4's sc0-only L2 exchange FAILED (stale L2 reads / mixed-mode
// hazard) -> cache-mode games abandoned; exchange stays on the proven R3 ops
// (agent-scope atomic store + sc0 sc1 validated poll, IC round trip ~700cy).
// R0's 5500cy period decomposed: (1) single-wave worker -> 64 ds_read_b128
// un-hidden ~770cy; (2) history NT-store BEFORE the poll -> its HBM ack
// (~900cy) inside the poll's vmcnt(0) every step; (3) detection = max over
// 32 producers at RT granularity. This round restructures:
//  - 8 workers/dir, each 256 thr / 4 waves, owns 32 cells. W slice 128x256
//    = 128KB: 120KB in LDS [j][tid] (conflict-free b128) + last 2 float4
//    per thread in registers (4-reg, demotion-proof unlike R2's 128-reg).
//    4 waves saturate the LDS pipe -> dot ~600cy (vs 770 un-hidden).
//  - wave = gate; per-row half-dot accumulation order IDENTICAL to R0 ->
//    bitwise-identical h trajectory.
//  - wave 0: activations for 32 cells, ONE mailbox line/worker store, poll
//    (unchanged protocol), h->LDS; other waves wait at barrier.
//  - history NT-store AFTER the poll: its ack drains under next step's dot.
//  - detection tail: max over 8 producers (8 lines), not 32.
// Tag protocol unchanged: 2-buffer parity ping-pong, 1-bit tag in mantissa
// LSB (<=1 ulp), each dword self-validating; poison 0xAA (bit0=0) and stale
// tags (etag(8190/8191)=0) mismatch etag=1 at t=0/1. Skew<=1 induction:
// overwriting parity-p at t+2 requires all produced t+1, which requires all
// observed t.
__global__ __launch_bounds__(256) void lstm_kernel(
    const float* __restrict__ pre_f, const float* __restrict__ pre_b,
    const float* __restrict__ whh_f, const float* __restrict__ whh_b,
    const float* __restrict__ h0_f, const float* __restrict__ c0_f,
    const float* __restrict__ h0_b, const float* __restrict__ c0_b,
    float* __restrict__ hs_f, float* __restrict__ hs_b,
    unsigned* __restrict__ mbox)
{
    const int b  = blockIdx.x;       // 0..15
    const int d  = b & 1;            // direction
    const int cb = b >> 1;           // worker id 0..7
    const int cell0 = cb * 32;

    const float* pre = d ? pre_b : pre_f;
    const float* whh = d ? whh_b : whh_f;
    const float* h0  = d ? h0_b : h0_f;
    const float* c0  = d ? c0_b : c0_f;
    float* hs        = d ? hs_b : hs_f;

    const int tid  = threadIdx.x;    // 0..255
    const int lane = tid & 63;
    const int wv   = tid >> 6;       // wave id == gate id (rows 32wv..32wv+31)
    const int r    = tid >> 1;       // local row 0..127
    const int half = tid & 1;        // k-half: [half*128, half*128+128)
    const int cl   = r & 31;         // cell within worker
    const int grow = wv * 256 + cell0 + cl;   // global gate row (0..1023)

    __shared__ __align__(16) float4 w4[30 * 256];   // 120 KB, [j][tid]
    __shared__ __align__(16) float  h_lds[256];
    __shared__ float gsum[128];                      // [gate][cell]

    // stage W: j=0..29 in LDS, j=30,31 in registers (4+4 VGPR, loop-invariant)
    float4 wr30, wr31;
    {
        const float4* src = (const float4*)(whh + (size_t)grow * H2N + half * 128);
#pragma unroll
        for (int j = 0; j < 30; j++) w4[j * 256 + tid] = src[j];
        wr30 = src[30]; wr31 = src[31];
    }
    if (tid < 64) ((float4*)h_lds)[tid] = ((const float4*)h0)[tid];
    float c = (wv == 0 && lane < 32) ? c0[cell0 + lane] : 0.f;
    __syncthreads();

    const float* pre_base = pre + grow;
    float pre_cur = (half == 0) ? pre_base[0] : 0.f;
    unsigned* mb_dir = mbox + d * 512;

    for (int t = 0; t < SLEN; t++) {
        // issue next pre early: resolves under this step's poll window
        float pre_next = (half == 0 && t < SLEN - 1) ? pre_base[(size_t)(t + 1) * G4] : 0.f;
        const unsigned etag = (((unsigned)t >> 1) & 1u) ^ 1u;
        unsigned* mb = mb_dir + (t & 1) * 256;

        // dot over this thread's k-half (identical accumulation order to R0)
        float a0 = pre_cur, a1 = 0.f, a2 = 0.f, a3 = 0.f;
        const float4* hr4 = (const float4*)(h_lds + half * 128);
#pragma unroll
        for (int j = 0; j < 30; j++) {
            float4 wvv = w4[j * 256 + tid];
            float4 hv  = hr4[j];
            a0 += wvv.x * hv.x; a1 += wvv.y * hv.y;
            a2 += wvv.z * hv.z; a3 += wvv.w * hv.w;
        }
        {
            float4 hv = hr4[30];
            a0 += wr30.x * hv.x; a1 += wr30.y * hv.y;
            a2 += wr30.z * hv.z; a3 += wr30.w * hv.w;
        }
        {
            float4 hv = hr4[31];
            a0 += wr31.x * hv.x; a1 += wr31.y * hv.y;
            a2 += wr31.z * hv.z; a3 += wr31.w * hv.w;
        }
        float sum = (a0 + a1) + (a2 + a3);
        sum += __shfl_xor(sum, 1, 64);   // combine the two k-halves of row r

        if (!half) gsum[wv * 32 + cl] = sum;   // even lanes, conflict-free
        __syncthreads();   // A: gate sums ready

        if (wv == 0) {
            unsigned hm = 0;
            if (lane < 32) {
                float s_i = gsum[lane];
                float s_f = gsum[32 + lane];
                float s_g = gsum[64 + lane];
                float s_o = gsum[96 + lane];
                float i_ = fast_sigmoid(s_i);
                float f_ = fast_sigmoid(s_f);
                float g_ = fast_tanh(s_g);
                float o_ = fast_sigmoid(s_o);
                c = f_ * c + i_ * g_;
                float h = o_ * fast_tanh(c);
                hm = (__float_as_uint(h) & ~1u) | etag;   // tag bit, <=1 ulp
                __hip_atomic_store(mb + cell0 + lane, hm,
                                   __ATOMIC_RELAXED, __HIP_MEMORY_SCOPE_AGENT);
            }

            // poll full mailbox: one validated dwordx4 per lane per round
            const unsigned* ms4 = mb + 4 * lane;
            u32x4 v;
            int spin = 0;
            for (;;) {
                asm volatile("global_load_dwordx4 %0, %1, off sc0 sc1\n\t"
                             "s_waitcnt vmcnt(0)"
                             : "=v"(v) : "v"(ms4) : "memory");
                if (!(((v.x ^ etag) | (v.y ^ etag) | (v.z ^ etag) | (v.w ^ etag)) & 1u))
                    break;
                if (++spin >= 300000) break;   // deadlock guard only
            }
            float4 hv4;
            hv4.x = __uint_as_float(v.x); hv4.y = __uint_as_float(v.y);
            hv4.z = __uint_as_float(v.z); hv4.w = __uint_as_float(v.w);
            *(float4*)(h_lds + 4 * lane) = hv4;

            // history for feats: AFTER the poll -> ack drains under next dot
            if (lane < 32)
                __builtin_nontemporal_store(hm,
                    (unsigned*)hs + (size_t)t * H2N + cell0 + lane);
        }
        __syncthreads();   // B: h_{t} visible in LDS for all waves
        pre_cur = pre_next;
    }
}

// ---------------- K3: feats = concat(hs_f[s], hs_b[S-1-s]) @ w_out^T + b_out ----------------
__global__ __launch_bounds__(256) void feats_kernel(
    const float* __restrict__ hs_f, const float* __restrict__ hs_b,
    const float* __restrict__ w_out, const float* __restrict__ b_out,
    float* __restrict__ feats)
{
    const int rs0 = blockIdx.x * 16;
    const int tid = threadIdx.x;
    const int r = tid >> 4, cc = tid & 15;

    __shared__ float Hs[16][516];   // row stride 2064 B (16B-aligned)
    for (int i = tid; i < 16 * 256; i += 256) {
        int rr = i >> 8, k = i & 255;
        Hs[rr][k]       = hs_f[(size_t)(rs0 + rr) * H2N + k];
        Hs[rr][256 + k] = hs_b[(size_t)(SLEN - 1 - (rs0 + rr)) * H2N + k];
    }
    __syncthreads();

    float acc = 0.f;
    const float* wr = w_out + (size_t)cc * 512;
    const float* hrow = Hs[r];
#pragma unroll 4
    for (int kq = 0; kq < 128; kq++) {
        float4 hv = *(const float4*)(hrow + 4 * kq);
        float4 wv = *(const float4*)(wr + 4 * kq);
        acc += hv.x * wv.x; acc += hv.y * wv.y;
        acc += hv.z * wv.z; acc += hv.w * wv.w;
    }
    feats[(size_t)(rs0 + r) * NTAG + cc] = acc + b_out[cc];
}

// ---------------- K4: Viterbi scan + backtrack (single wave, LDS back-ptrs) ----------------
__global__ __launch_bounds__(64) void viterbi_kernel(
    const float* __restrict__ feats, const float* __restrict__ trans,
    float* __restrict__ out)
{
    __shared__ unsigned char back_s[SLEN * 8];   // 65536 B, [t][tag/2] nibbles

    const int lane = threadIdx.x;
    const int nx = lane >> 2, pc = lane & 3;   // next tag, prev-chunk

    float tr[4];
#pragma unroll
    for (int j = 0; j < 4; j++) tr[j] = trans[nx * NTAG + pc * 4 + j];

    // score of tag g lives (replicated) in lanes 4g..4g+3
    float sc = (nx == 0) ? 0.f : NEGV;
    float fe = feats[nx];   // prefetch t=0

    for (int t = 0; t < SLEN; t++) {
        float fe_next = (t < SLEN - 1) ? feats[(size_t)(t + 1) * NTAG + nx] : 0.f;

        float bv; int bi;
#pragma unroll
        for (int j = 0; j < 4; j++) {
            float s = __shfl(sc, 4 * (pc * 4 + j), 64);
            float cand = s + tr[j];
            if (j == 0) { bv = cand; bi = pc * 4; }
            else if (cand > bv) { bv = cand; bi = pc * 4 + j; }
        }
        // combine across the 4 prev-chunks; first-max semantics (tie -> smaller idx)
#pragma unroll
        for (int off = 1; off < 4; off <<= 1) {
            float ov = __shfl_xor(bv, off, 64);
            int   oi = __shfl_xor(bi, off, 64);
            if (ov > bv || (ov == bv && oi < bi)) { bv = ov; bi = oi; }
        }
        // nibble-pack: lane (nx even, pc==0) stores [bi(nx) | bi(nx+1)<<4]
        int bi_part = __shfl(bi, (nx | 1) * 4, 64);
        if (pc == 0 && (nx & 1) == 0)
            back_s[t * 8 + (nx >> 1)] = (unsigned char)((bi & 15) | (bi_part << 4));
        sc = bv + fe;
        fe = fe_next;
    }

    // final = last + trans[END=1]; first-argmax
    float bestv = 0.f; int besti = 0;
#pragma unroll
    for (int j = 0; j < NTAG; j++) {
        float sj = __shfl(sc, 4 * j, 64);
        float fj = sj + trans[1 * NTAG + j];
        if (j == 0) { bestv = fj; besti = 0; }
        else if (fj > bestv) { bestv = fj; besti = j; }
    }
    __syncthreads();

    if (lane == 0) {
        out[0] = bestv;
        int cur = besti;
        for (int t = SLEN - 1; t >= 1; t--) {
            out[1 + t] = (float)cur;
            unsigned char byte = back_s[t * 8 + (cur >> 1)];
            cur = (cur & 1) ? (byte >> 4) : (byte & 15);
        }
        out[1] = (float)cur;
    }
}

extern "C" void kernel_launch(void* const* d_in, const int* in_sizes, int n_in,
                              void* d_out, int out_size, void* d_ws, size_t ws_size,
                              hipStream_t stream) {
    const int*   sent   = (const int*)d_in[0];
    const float* emb    = (const float*)d_in[1];
    const float* w_ih_f = (const float*)d_in[2];
    const float* w_hh_f = (const float*)d_in[3];
    const float* b_f    = (const float*)d_in[4];
    const float* w_ih_b = (const float*)d_in[5];
    const float* w_hh_b = (const float*)d_in[6];
    const float* b_b    = (const float*)d_in[7];
    const float* h0_f   = (const float*)d_in[8];
    const float* c0_f   = (const float*)d_in[9];
    const float* h0_b   = (const float*)d_in[10];
    const float* c0_b   = (const float*)d_in[11];
    const float* w_out  = (const float*)d_in[12];
    const float* b_out  = (const float*)d_in[13];
    const float* trans  = (const float*)d_in[14];
    float* out = (float*)d_out;

    if (ws_size < WS_NEEDED) return;  // visible failure, no OOB writes

    float* ws = (float*)d_ws;
    float* pre_f = ws + OFF_PRE_F;
    float* pre_b = ws + OFF_PRE_B;
    float* hs_f  = ws + OFF_HS_F;
    float* hs_b  = ws + OFF_HS_B;
    float* feats = ws + OFF_FEATS;
    unsigned* mbox = (unsigned*)(ws + OFF_MBOX);

    gemm_pre<<<dim3(128, 16, 2), 256, 0, stream>>>(sent, emb, w_ih_f, b_f, w_ih_b, b_b, pre_f, pre_b);
    lstm_kernel<<<16, 256, 0, stream>>>(pre_f, pre_b, w_hh_f, w_hh_b,
                                        h0_f, c0_f, h0_b, c0_b, hs_f, hs_b, mbox);
    feats_kernel<<<512, 256, 0, stream>>>(hs_f, hs_b, w_out, b_out, feats);
    viterbi_kernel<<<1, 64, 0, stream>>>(feats, trans, out);
}

// Round 6
// 20145.213 us; speedup vs baseline: 1.3037x; 1.0581x over previous
//
#include <hip/hip_runtime.h>
#include <math.h>

#define SLEN 8192
#define DIM  256
#define H2N  256
#define G4   1024
#define NTAG 16
#define NEGV (-10000.0f)

// ws layout (float offsets unless noted)
#define OFF_PRE_F   0
#define OFF_PRE_B   (SLEN*G4)
#define OFF_HS_F    (2*SLEN*G4)
#define OFF_HS_B    (2*SLEN*G4 + SLEN*H2N)
#define OFF_FEATS   (2*SLEN*G4 + 2*SLEN*H2N)
#define OFF_MBOX    (OFF_FEATS + SLEN*NTAG)      // 2 dir x 2 buf x 256 u32
#define WS_NEEDED   ((size_t)(OFF_MBOX + 1024) * 4)

typedef unsigned int u32x4 __attribute__((ext_vector_type(4)));

// ---------------- K1: pre = gather(emb, sentence[±]) @ w_ih^T + b ----------------
__global__ __launch_bounds__(256) void gemm_pre(
    const int* __restrict__ sent, const float* __restrict__ emb,
    const float* __restrict__ wf, const float* __restrict__ bf,
    const float* __restrict__ wb, const float* __restrict__ bb,
    float* __restrict__ pre_f, float* __restrict__ pre_b)
{
    const int dir = blockIdx.z;
    const float* w    = dir ? wb : wf;
    const float* bias = dir ? bb : bf;
    float* out        = dir ? pre_b : pre_f;
    const int m0 = blockIdx.x * 64, n0 = blockIdx.y * 64;

    __shared__ float As[16][68];   // [k][m], row stride 272 B (16B-aligned)
    __shared__ float Bs[16][68];   // [k][n]
    __shared__ int   sidx[64];

    const int tid = threadIdx.x;
    const int tx = tid & 15, ty = tid >> 4;

    if (tid < 64) {
        int m = m0 + tid;
        int pos = dir ? (SLEN - 1 - m) : m;
        sidx[tid] = sent[pos];
    }
    __syncthreads();

    float acc[4][4];
#pragma unroll
    for (int i = 0; i < 4; i++)
#pragma unroll
        for (int j = 0; j < 4; j++) acc[i][j] = 0.f;

    const int lr = tid >> 2, lc = (tid & 3) * 4;

    for (int k0 = 0; k0 < DIM; k0 += 16) {
        float4 av = *(const float4*)(emb + (size_t)sidx[lr] * DIM + k0 + lc);
        float4 bv = *(const float4*)(w + (size_t)(n0 + lr) * DIM + k0 + lc);
        As[lc+0][lr] = av.x; As[lc+1][lr] = av.y; As[lc+2][lr] = av.z; As[lc+3][lr] = av.w;
        Bs[lc+0][lr] = bv.x; Bs[lc+1][lr] = bv.y; Bs[lc+2][lr] = bv.z; Bs[lc+3][lr] = bv.w;
        __syncthreads();
#pragma unroll
        for (int k = 0; k < 16; k++) {
            float4 a4 = *(const float4*)&As[k][ty * 4];
            float4 b4 = *(const float4*)&Bs[k][tx * 4];
            float a[4] = {a4.x, a4.y, a4.z, a4.w};
            float b[4] = {b4.x, b4.y, b4.z, b4.w};
#pragma unroll
            for (int i = 0; i < 4; i++)
#pragma unroll
                for (int j = 0; j < 4; j++) acc[i][j] += a[i] * b[j];
        }
        __syncthreads();
    }

    float4 b4 = *(const float4*)(bias + n0 + tx*4);
#pragma unroll
    for (int i = 0; i < 4; i++) {
        float4 v;
        v.x = acc[i][0] + b4.x; v.y = acc[i][1] + b4.y;
        v.z = acc[i][2] + b4.z; v.w = acc[i][3] + b4.w;
        *(float4*)(out + (size_t)(m0 + ty*4 + i) * G4 + n0 + tx*4) = v;
    }
}

__device__ __forceinline__ float fast_sigmoid(float x) {
    return 1.f / (1.f + __expf(-x));
}
__device__ __forceinline__ float fast_tanh(float x) {
    float xc = fminf(fmaxf(x, -15.f), 15.f);
    float e = __expf(2.f * xc);
    return (e - 1.f) / (e + 1.f);
}

// ---------------- K2: two LSTMs, 8 FAT workers/dir, PIPELINED poll ----------------
// R13 analysis: across 5 structural variants the period sticks at ~5250cy
// while per-CU VALU says compute is ~270cy -> ~5000cy is poll memory-wait.
// The serial poll (load -> vmcnt(0) -> check -> reissue) samples the mailbox
// once per IC round trip (RT ~1500-2500cy): detection = alignment waste (up
// to RT) + detecting load (RT). This round attacks exactly that term:
//  (a) 4-deep software-pipelined poll: 4 outstanding tagged dwordx4 loads,
//      primed with ~128cy stagger (s_sleep(2)); steady state waits
//      vmcnt(3), checks the oldest, reissues it. Sampling interval drops
//      RT -> ~128cy; detection after last commit ~RT/2+128 instead of 2RT.
//      sched_barrier(0) after each waitcnt (rule #18: compiler hoists
//      register-only checks past inline-asm waitcnt). vmcnt(0) drain before
//      priming so vmcnt counts only poll loads. Tags still validate every
//      word -> sampling rate cannot affect correctness.
//  (b) self-exchange elimination: wave0 lanes<32 write their own tagged hm
//      directly into h_lds; poll lanes whose 4 cells lie in the own chunk
//      (lane>>3==cb) skip the wait. Removes a full RT when self is the
//      last producer. Same tagged values as the mailbox -> trajectories of
//      all workers stay bitwise identical.
// Everything else = R5 (verified): 8 workers/dir, 4 waves, W 120KB LDS +
// 2 float4/thread regs, accumulation order identical to R0, history
// NT-store after poll, 2-buffer parity ping-pong + 1-bit mantissa-LSB tag
// (<=1 ulp), skew<=1 induction unchanged.
__global__ __launch_bounds__(256) void lstm_kernel(
    const float* __restrict__ pre_f, const float* __restrict__ pre_b,
    const float* __restrict__ whh_f, const float* __restrict__ whh_b,
    const float* __restrict__ h0_f, const float* __restrict__ c0_f,
    const float* __restrict__ h0_b, const float* __restrict__ c0_b,
    float* __restrict__ hs_f, float* __restrict__ hs_b,
    unsigned* __restrict__ mbox)
{
    const int b  = blockIdx.x;       // 0..15
    const int d  = b & 1;            // direction
    const int cb = b >> 1;           // worker id 0..7
    const int cell0 = cb * 32;

    const float* pre = d ? pre_b : pre_f;
    const float* whh = d ? whh_b : whh_f;
    const float* h0  = d ? h0_b : h0_f;
    const float* c0  = d ? c0_b : c0_f;
    float* hs        = d ? hs_b : hs_f;

    const int tid  = threadIdx.x;    // 0..255
    const int lane = tid & 63;
    const int wv   = tid >> 6;       // wave id == gate id (rows 32wv..32wv+31)
    const int r    = tid >> 1;       // local row 0..127
    const int half = tid & 1;        // k-half: [half*128, half*128+128)
    const int cl   = r & 31;         // cell within worker
    const int grow = wv * 256 + cell0 + cl;   // global gate row (0..1023)

    __shared__ __align__(16) float4 w4[30 * 256];   // 120 KB, [j][tid]
    __shared__ __align__(16) float  h_lds[256];
    __shared__ float gsum[128];                      // [gate][cell]

    // stage W: j=0..29 in LDS, j=30,31 in registers (4+4 VGPR, loop-invariant)
    float4 wr30, wr31;
    {
        const float4* src = (const float4*)(whh + (size_t)grow * H2N + half * 128);
#pragma unroll
        for (int j = 0; j < 30; j++) w4[j * 256 + tid] = src[j];
        wr30 = src[30]; wr31 = src[31];
    }
    if (tid < 64) ((float4*)h_lds)[tid] = ((const float4*)h0)[tid];
    float c = (wv == 0 && lane < 32) ? c0[cell0 + lane] : 0.f;
    __syncthreads();

    const float* pre_base = pre + grow;
    float pre_cur = (half == 0) ? pre_base[0] : 0.f;
    unsigned* mb_dir = mbox + d * 512;
    const bool own = ((lane >> 3) == cb);   // this lane's 4 poll cells are ours

#define ISSUE(B) asm volatile("global_load_dwordx4 %0, %1, off sc0 sc1" \
                              : "=&v"(B) : "v"(ms4) : "memory")
#define WAIT3()  do { asm volatile("s_waitcnt vmcnt(3)" ::: "memory"); \
                      __builtin_amdgcn_sched_barrier(0); } while (0)
#define TAGOK(B) (!((((B).x ^ etag) | ((B).y ^ etag) | \
                     ((B).z ^ etag) | ((B).w ^ etag)) & 1u))

    for (int t = 0; t < SLEN; t++) {
        // issue next pre early: resolves long before the poll drain
        float pre_next = (half == 0 && t < SLEN - 1) ? pre_base[(size_t)(t + 1) * G4] : 0.f;
        const unsigned etag = (((unsigned)t >> 1) & 1u) ^ 1u;
        unsigned* mb = mb_dir + (t & 1) * 256;

        // dot over this thread's k-half (identical accumulation order to R0)
        float a0 = pre_cur, a1 = 0.f, a2 = 0.f, a3 = 0.f;
        const float4* hr4 = (const float4*)(h_lds + half * 128);
#pragma unroll
        for (int j = 0; j < 30; j++) {
            float4 wvv = w4[j * 256 + tid];
            float4 hv  = hr4[j];
            a0 += wvv.x * hv.x; a1 += wvv.y * hv.y;
            a2 += wvv.z * hv.z; a3 += wvv.w * hv.w;
        }
        {
            float4 hv = hr4[30];
            a0 += wr30.x * hv.x; a1 += wr30.y * hv.y;
            a2 += wr30.z * hv.z; a3 += wr30.w * hv.w;
        }
        {
            float4 hv = hr4[31];
            a0 += wr31.x * hv.x; a1 += wr31.y * hv.y;
            a2 += wr31.z * hv.z; a3 += wr31.w * hv.w;
        }
        float sum = (a0 + a1) + (a2 + a3);
        sum += __shfl_xor(sum, 1, 64);   // combine the two k-halves of row r

        if (!half) gsum[wv * 32 + cl] = sum;   // even lanes, conflict-free
        __syncthreads();   // A: gate sums ready

        if (wv == 0) {
            unsigned hm = 0;
            if (lane < 32) {
                float s_i = gsum[lane];
                float s_f = gsum[32 + lane];
                float s_g = gsum[64 + lane];
                float s_o = gsum[96 + lane];
                float i_ = fast_sigmoid(s_i);
                float f_ = fast_sigmoid(s_f);
                float g_ = fast_tanh(s_g);
                float o_ = fast_sigmoid(s_o);
                c = f_ * c + i_ * g_;
                float h = o_ * fast_tanh(c);
                hm = (__float_as_uint(h) & ~1u) | etag;   // tag bit, <=1 ulp
                __hip_atomic_store(mb + cell0 + lane, hm,
                                   __ATOMIC_RELAXED, __HIP_MEMORY_SCOPE_AGENT);
                // self-exchange elimination: own h -> LDS directly (same
                // tagged value others will read from the mailbox)
                h_lds[cell0 + lane] = __uint_as_float(hm);
            }

            // pipelined poll of the other 7 workers' lines
            const unsigned* ms4 = mb + 4 * lane;
            if (!own) {
                u32x4 b0, b1, b2, b3, v;
                // drain pre_next + mailbox store so vmcnt tracks polls only
                asm volatile("s_waitcnt vmcnt(0)" ::: "memory");
                __builtin_amdgcn_sched_barrier(0);
                ISSUE(b0); __builtin_amdgcn_s_sleep(2);
                ISSUE(b1); __builtin_amdgcn_s_sleep(2);
                ISSUE(b2); __builtin_amdgcn_s_sleep(2);
                ISSUE(b3);
                int spin = 0;
                for (;;) {
                    WAIT3();
                    if (TAGOK(b0)) { v = b0; break; }
                    ISSUE(b0);
                    WAIT3();
                    if (TAGOK(b1)) { v = b1; break; }
                    ISSUE(b1);
                    WAIT3();
                    if (TAGOK(b2)) { v = b2; break; }
                    ISSUE(b2);
                    WAIT3();
                    if (TAGOK(b3)) { v = b3; break; }
                    ISSUE(b3);
                    if (++spin >= 100000) { v = b0; break; }   // deadlock guard
                }
                float4 hv4;
                hv4.x = __uint_as_float(v.x); hv4.y = __uint_as_float(v.y);
                hv4.z = __uint_as_float(v.z); hv4.w = __uint_as_float(v.w);
                *(float4*)(h_lds + 4 * lane) = hv4;
            }

            // history for feats: AFTER the poll -> ack drains under next dot
            if (lane < 32)
                __builtin_nontemporal_store(hm,
                    (unsigned*)hs + (size_t)t * H2N + cell0 + lane);
        }
        __syncthreads();   // B: h_t visible in LDS for all waves (drains vm+lgkm)
        pre_cur = pre_next;
    }
#undef ISSUE
#undef WAIT3
#undef TAGOK
}

// ---------------- K3: feats = concat(hs_f[s], hs_b[S-1-s]) @ w_out^T + b_out ----------------
__global__ __launch_bounds__(256) void feats_kernel(
    const float* __restrict__ hs_f, const float* __restrict__ hs_b,
    const float* __restrict__ w_out, const float* __restrict__ b_out,
    float* __restrict__ feats)
{
    const int rs0 = blockIdx.x * 16;
    const int tid = threadIdx.x;
    const int r = tid >> 4, cc = tid & 15;

    __shared__ float Hs[16][516];   // row stride 2064 B (16B-aligned)
    for (int i = tid; i < 16 * 256; i += 256) {
        int rr = i >> 8, k = i & 255;
        Hs[rr][k]       = hs_f[(size_t)(rs0 + rr) * H2N + k];
        Hs[rr][256 + k] = hs_b[(size_t)(SLEN - 1 - (rs0 + rr)) * H2N + k];
    }
    __syncthreads();

    float acc = 0.f;
    const float* wr = w_out + (size_t)cc * 512;
    const float* hrow = Hs[r];
#pragma unroll 4
    for (int kq = 0; kq < 128; kq++) {
        float4 hv = *(const float4*)(hrow + 4 * kq);
        float4 wv = *(const float4*)(wr + 4 * kq);
        acc += hv.x * wv.x; acc += hv.y * wv.y;
        acc += hv.z * wv.z; acc += hv.w * wv.w;
    }
    feats[(size_t)(rs0 + r) * NTAG + cc] = acc + b_out[cc];
}

// ---------------- K4: Viterbi scan + backtrack (single wave, LDS back-ptrs) ----------------
__global__ __launch_bounds__(64) void viterbi_kernel(
    const float* __restrict__ feats, const float* __restrict__ trans,
    float* __restrict__ out)
{
    __shared__ unsigned char back_s[SLEN * 8];   // 65536 B, [t][tag/2] nibbles

    const int lane = threadIdx.x;
    const int nx = lane >> 2, pc = lane & 3;   // next tag, prev-chunk

    float tr[4];
#pragma unroll
    for (int j = 0; j < 4; j++) tr[j] = trans[nx * NTAG + pc * 4 + j];

    // score of tag g lives (replicated) in lanes 4g..4g+3
    float sc = (nx == 0) ? 0.f : NEGV;
    float fe = feats[nx];   // prefetch t=0

    for (int t = 0; t < SLEN; t++) {
        float fe_next = (t < SLEN - 1) ? feats[(size_t)(t + 1) * NTAG + nx] : 0.f;

        float bv; int bi;
#pragma unroll
        for (int j = 0; j < 4; j++) {
            float s = __shfl(sc, 4 * (pc * 4 + j), 64);
            float cand = s + tr[j];
            if (j == 0) { bv = cand; bi = pc * 4; }
            else if (cand > bv) { bv = cand; bi = pc * 4 + j; }
        }
        // combine across the 4 prev-chunks; first-max semantics (tie -> smaller idx)
#pragma unroll
        for (int off = 1; off < 4; off <<= 1) {
            float ov = __shfl_xor(bv, off, 64);
            int   oi = __shfl_xor(bi, off, 64);
            if (ov > bv || (ov == bv && oi < bi)) { bv = ov; bi = oi; }
        }
        // nibble-pack: lane (nx even, pc==0) stores [bi(nx) | bi(nx+1)<<4]
        int bi_part = __shfl(bi, (nx | 1) * 4, 64);
        if (pc == 0 && (nx & 1) == 0)
            back_s[t * 8 + (nx >> 1)] = (unsigned char)((bi & 15) | (bi_part << 4));
        sc = bv + fe;
        fe = fe_next;
    }

    // final = last + trans[END=1]; first-argmax
    float bestv = 0.f; int besti = 0;
#pragma unroll
    for (int j = 0; j < NTAG; j++) {
        float sj = __shfl(sc, 4 * j, 64);
        float fj = sj + trans[1 * NTAG + j];
        if (j == 0) { bestv = fj; besti = 0; }
        else if (fj > bestv) { bestv = fj; besti = j; }
    }
    __syncthreads();

    if (lane == 0) {
        out[0] = bestv;
        int cur = besti;
        for (int t = SLEN - 1; t >= 1; t--) {
            out[1 + t] = (float)cur;
            unsigned char byte = back_s[t * 8 + (cur >> 1)];
            cur = (cur & 1) ? (byte >> 4) : (byte & 15);
        }
        out[1] = (float)cur;
    }
}

extern "C" void kernel_launch(void* const* d_in, const int* in_sizes, int n_in,
                              void* d_out, int out_size, void* d_ws, size_t ws_size,
                              hipStream_t stream) {
    const int*   sent   = (const int*)d_in[0];
    const float* emb    = (const float*)d_in[1];
    const float* w_ih_f = (const float*)d_in[2];
    const float* w_hh_f = (const float*)d_in[3];
    const float* b_f    = (const float*)d_in[4];
    const float* w_ih_b = (const float*)d_in[5];
    const float* w_hh_b = (const float*)d_in[6];
    const float* b_b    = (const float*)d_in[7];
    const float* h0_f   = (const float*)d_in[8];
    const float* c0_f   = (const float*)d_in[9];
    const float* h0_b   = (const float*)d_in[10];
    const float* c0_b   = (const float*)d_in[11];
    const float* w_out  = (const float*)d_in[12];
    const float* b_out  = (const float*)d_in[13];
    const float* trans  = (const float*)d_in[14];
    float* out = (float*)d_out;

    if (ws_size < WS_NEEDED) return;  // visible failure, no OOB writes

    float* ws = (float*)d_ws;
    float* pre_f = ws + OFF_PRE_F;
    float* pre_b = ws + OFF_PRE_B;
    float* hs_f  = ws + OFF_HS_F;
    float* hs_b  = ws + OFF_HS_B;
    float* feats = ws + OFF_FEATS;
    unsigned* mbox = (unsigned*)(ws + OFF_MBOX);

    gemm_pre<<<dim3(128, 16, 2), 256, 0, stream>>>(sent, emb, w_ih_f, b_f, w_ih_b, b_b, pre_f, pre_b);
    lstm_kernel<<<16, 256, 0, stream>>>(pre_f, pre_b, w_hh_f, w_hh_b,
                                        h0_f, c0_f, h0_b, c0_b, hs_f, hs_b, mbox);
    feats_kernel<<<512, 256, 0, stream>>>(hs_f, hs_b, w_out, b_out, feats);
    viterbi_kernel<<<1, 64, 0, stream>>>(feats, trans, out);
}

// Round 8
// 19808.546 us; speedup vs baseline: 1.3259x; 1.0170x over previous
//
#include <hip/hip_runtime.h>
#include <math.h>

#define SLEN 8192
#define DIM  256
#define H2N  256
#define G4   1024
#define NTAG 16
#define NEGV (-10000.0f)

// ws layout (float offsets unless noted)
#define OFF_PRE_F   0
#define OFF_PRE_B   (SLEN*G4)
#define OFF_HS_F    (2*SLEN*G4)
#define OFF_HS_B    (2*SLEN*G4 + SLEN*H2N)
#define OFF_FEATS   (2*SLEN*G4 + 2*SLEN*H2N)
#define WS_NEEDED   ((size_t)(OFF_FEATS + SLEN*NTAG) * 4)

typedef unsigned int u32x4 __attribute__((ext_vector_type(4)));
typedef __fp16 h2_t __attribute__((ext_vector_type(2)));

__device__ __forceinline__ unsigned pack2(float x, float y) {
#if __has_builtin(__builtin_amdgcn_cvt_pkrtz)
    return __builtin_bit_cast(unsigned, __builtin_amdgcn_cvt_pkrtz(x, y));
#else
    union { __fp16 h[2]; unsigned u; } t;
    t.h[0] = (__fp16)x; t.h[1] = (__fp16)y;
    return t.u;
#endif
}

#if __has_builtin(__builtin_amdgcn_fdot2)
__device__ __forceinline__ float fdot2(unsigned a, unsigned b, float c) {
    return __builtin_amdgcn_fdot2(__builtin_bit_cast(h2_t, a),
                                  __builtin_bit_cast(h2_t, b), c, false);
}
#else
__device__ __forceinline__ float fdot2(unsigned a, unsigned b, float c) {
    union { unsigned u; __fp16 h[2]; } ua, ub;
    ua.u = a; ub.u = b;
    return c + (float)ua.h[0] * (float)ub.h[0] + (float)ua.h[1] * (float)ub.h[1];
}
#endif

// in-register reduce over the 8 k-group lanes (lane bits 0..2). All three
// DPP patterns are SYMMETRIC (involutions) -> no rotation-direction risk:
//   0xB1 = quad_perm[1,0,3,2]  (lane ^ 1)
//   0x4E = quad_perm[2,3,0,1]  (lane ^ 2)
//   0x141 = ROW_HALF_MIRROR    (lane ^ 7 within each 8-lane half-row;
//           each half-row is one rl group, so kg0 <- kg7 = other quad's sum)
template <int CTRL>
__device__ __forceinline__ float dpp_add(float x) {
    int v = __builtin_amdgcn_update_dpp(0, __float_as_int(x), CTRL, 0xF, 0xF, true);
    return x + __int_as_float(v);
}

// ---------------- K1: pre = gather(emb, sentence[±]) @ w_ih^T + b ----------------
__global__ __launch_bounds__(256) void gemm_pre(
    const int* __restrict__ sent, const float* __restrict__ emb,
    const float* __restrict__ wf, const float* __restrict__ bf,
    const float* __restrict__ wb, const float* __restrict__ bb,
    float* __restrict__ pre_f, float* __restrict__ pre_b)
{
    const int dir = blockIdx.z;
    const float* w    = dir ? wb : wf;
    const float* bias = dir ? bb : bf;
    float* out        = dir ? pre_b : pre_f;
    const int m0 = blockIdx.x * 64, n0 = blockIdx.y * 64;

    __shared__ float As[16][68];   // [k][m], row stride 272 B (16B-aligned)
    __shared__ float Bs[16][68];   // [k][n]
    __shared__ int   sidx[64];

    const int tid = threadIdx.x;
    const int tx = tid & 15, ty = tid >> 4;

    if (tid < 64) {
        int m = m0 + tid;
        int pos = dir ? (SLEN - 1 - m) : m;
        sidx[tid] = sent[pos];
    }
    __syncthreads();

    float acc[4][4];
#pragma unroll
    for (int i = 0; i < 4; i++)
#pragma unroll
        for (int j = 0; j < 4; j++) acc[i][j] = 0.f;

    const int lr = tid >> 2, lc = (tid & 3) * 4;

    for (int k0 = 0; k0 < DIM; k0 += 16) {
        float4 av = *(const float4*)(emb + (size_t)sidx[lr] * DIM + k0 + lc);
        float4 bv = *(const float4*)(w + (size_t)(n0 + lr) * DIM + k0 + lc);
        As[lc+0][lr] = av.x; As[lc+1][lr] = av.y; As[lc+2][lr] = av.z; As[lc+3][lr] = av.w;
        Bs[lc+0][lr] = bv.x; Bs[lc+1][lr] = bv.y; Bs[lc+2][lr] = bv.z; Bs[lc+3][lr] = bv.w;
        __syncthreads();
#pragma unroll
        for (int k = 0; k < 16; k++) {
            float4 a4 = *(const float4*)&As[k][ty * 4];
            float4 b4 = *(const float4*)&Bs[k][tx * 4];
            float a[4] = {a4.x, a4.y, a4.z, a4.w};
            float b[4] = {b4.x, b4.y, b4.z, b4.w};
#pragma unroll
            for (int i = 0; i < 4; i++)
#pragma unroll
                for (int j = 0; j < 4; j++) acc[i][j] += a[i] * b[j];
        }
        __syncthreads();
    }

    float4 b4 = *(const float4*)(bias + n0 + tx*4);
#pragma unroll
    for (int i = 0; i < 4; i++) {
        float4 v;
        v.x = acc[i][0] + b4.x; v.y = acc[i][1] + b4.y;
        v.z = acc[i][2] + b4.z; v.w = acc[i][3] + b4.w;
        *(float4*)(out + (size_t)(m0 + ty*4 + i) * G4 + n0 + tx*4) = v;
    }
}

__device__ __forceinline__ float fast_sigmoid(float x) {
    return 1.f / (1.f + __expf(-x));
}
__device__ __forceinline__ float fast_tanh(float x) {
    float xc = fminf(fmaxf(x, -15.f), 15.f);
    float e = __expf(2.f * xc);
    return (e - 1.f) / (e + 1.f);
}

// ---------------- K2: ONE CU per direction — zero cross-block exchange ----------------
// R15 (= R14 design, compile-fixed): R0-R6 pinned the floor — ANY cross-block
// h-exchange costs ~5000cy/step at the IC coherence point, invariant to
// producer count, placement, poll shaping, pipelined sampling. Eliminate
// exchange: the whole direction on ONE CU. W (1MB fp32) fits in f16 (512KB):
// 384KB in VGPRs (rows 0..11 of 16 per thread = 192 regs) + 128KB LDS
// (rows 12..15). 512 threads / 8 waves.
//  - thread (slot=w*8+rl, kg=l&7) owns rows {slot+64i, i=0..15}, ks
//    [kg*32, kg*32+32) as 16 packed half2 per row.
//  - per row: 16 v_dot2_f32_f16 (fp32 accumulate, 2-way ILP), then 3
//    symmetric DPP adds (0xB1, 0x4E, 0x141) reduce the 8 kg lanes
//    in-register -> kg0 lane holds the full gate-row sum. No LDS, no
//    ds_bpermute on the reduction path.
//  - kg0 lanes write gate sums to gsum[1024] as float4, XOR-bank-swizzled
//    (block b at slot*16 + ((b^(slot&3))<<2)) to cut act-read conflicts.
//  - barrier; threads<256: gates = gsum + pre(t) [prefetched], sigmoid/tanh,
//    fp32 c-state in regs, h -> f16 into hbuf (512B broadcast) + f16-rounded
//    fp32 h -> history (NT store, off critical path); prefetch pre(t+1);
//    barrier.
// Numerics: W,h f16 (rel ~5e-4), fp32 accumulation/gates/c-state.
// Step cost = LDS BW (~130KB/step ~1100cy) overlapped with VALU
// (~1300cy/SIMD) + 2 barriers -> ~2100-2800cy vs 5250 with exchange.
__global__ __launch_bounds__(512) void lstm_kernel(
    const float* __restrict__ pre_f, const float* __restrict__ pre_b,
    const float* __restrict__ whh_f, const float* __restrict__ whh_b,
    const float* __restrict__ h0_f, const float* __restrict__ c0_f,
    const float* __restrict__ h0_b, const float* __restrict__ c0_b,
    float* __restrict__ hs_f, float* __restrict__ hs_b)
{
    const int d = blockIdx.x;            // 0..1: direction
    const float* pre = d ? pre_b : pre_f;
    const float* whh = d ? whh_b : whh_f;
    const float* h0  = d ? h0_b : h0_f;
    const float* c0  = d ? c0_b : c0_f;
    float* hs        = d ? hs_b : hs_f;

    const int tid = threadIdx.x;         // 0..511
    const int l   = tid & 63;
    const int w   = tid >> 6;            // wave 0..7
    const int kg  = l & 7;               // k-group (32 ks)
    const int rl  = l >> 3;              // row-lane 0..7
    const int slot = w * 8 + rl;         // 0..63
    const int k0 = kg * 32;

    __shared__ __align__(16) u32x4  wlds[16][512];  // 128 KB: rows 12..15
    __shared__ __align__(16) __fp16 hbuf[256];      // 512 B broadcast h
    __shared__ __align__(16) float  gsum[1024];     // 4 KB swizzled gate sums

    // ---- stage W -> f16: rows 0..11 to VGPRs, 12..15 to LDS ----
    unsigned wreg[12][16];
#pragma unroll
    for (int i = 0; i < 16; i++) {
        const float* wsrc = whh + (size_t)(slot + 64 * i) * H2N + k0;
        unsigned pk[16];
#pragma unroll
        for (int q = 0; q < 8; q++) {
            float4 v = *(const float4*)(wsrc + 4 * q);
            pk[2 * q]     = pack2(v.x, v.y);
            pk[2 * q + 1] = pack2(v.z, v.w);
        }
        if (i < 12) {
#pragma unroll
            for (int p = 0; p < 16; p++) wreg[i][p] = pk[p];
        } else {
#pragma unroll
            for (int c4 = 0; c4 < 4; c4++) {
                u32x4 vv;
                vv.x = pk[4*c4+0]; vv.y = pk[4*c4+1];
                vv.z = pk[4*c4+2]; vv.w = pk[4*c4+3];
                wlds[(i - 12) * 4 + c4][tid] = vv;
            }
        }
    }

    // ---- init: h0 -> f16 broadcast buffer, c-state + pre(0) in act regs ----
    float cst = 0.f, prg0 = 0.f, prg1 = 0.f, prg2 = 0.f, prg3 = 0.f;
    if (tid < 256) {
        hbuf[tid] = (__fp16)h0[tid];
        cst  = c0[tid];
        prg0 = pre[0 * 256 + tid];
        prg1 = pre[1 * 256 + tid];
        prg2 = pre[2 * 256 + tid];
        prg3 = pre[3 * 256 + tid];
    }
    __syncthreads();

    for (int t = 0; t < SLEN; t++) {
        // ---- load h (broadcast, packed f16 pairs) into regs ----
        unsigned hreg[16];
        {
            const u32x4* hp = (const u32x4*)((const char*)hbuf + kg * 64);
#pragma unroll
            for (int j = 0; j < 4; j++) {
                u32x4 hv = hp[j];
                hreg[4*j+0] = hv.x; hreg[4*j+1] = hv.y;
                hreg[4*j+2] = hv.z; hreg[4*j+3] = hv.w;
            }
        }

        // ---- 16 gate-row partial dots + DPP reduce + swizzled gsum write ----
#pragma unroll
        for (int b = 0; b < 4; b++) {
            float sv[4];
#pragma unroll
            for (int ii = 0; ii < 4; ii++) {
                const int i = 4 * b + ii;
                float a0 = 0.f, a1 = 0.f;
                if (i < 12) {
#pragma unroll
                    for (int p = 0; p < 16; p += 2) {
                        a0 = fdot2(wreg[i][p],     hreg[p],     a0);
                        a1 = fdot2(wreg[i][p + 1], hreg[p + 1], a1);
                    }
                } else {
#pragma unroll
                    for (int c4 = 0; c4 < 4; c4++) {
                        u32x4 wc = wlds[(i - 12) * 4 + c4][tid];
                        a0 = fdot2(wc.x, hreg[4*c4+0], a0);
                        a1 = fdot2(wc.y, hreg[4*c4+1], a1);
                        a0 = fdot2(wc.z, hreg[4*c4+2], a0);
                        a1 = fdot2(wc.w, hreg[4*c4+3], a1);
                    }
                }
                float a = a0 + a1;
                a = dpp_add<0xB1>(a);    // + (kg^1)
                a = dpp_add<0x4E>(a);    // + (kg^2)
                a = dpp_add<0x141>(a);   // + (kg^7): other quad (half-mirror)
                sv[ii] = a;
            }
            if (kg == 0) {
                float4 o; o.x = sv[0]; o.y = sv[1]; o.z = sv[2]; o.w = sv[3];
                *(float4*)(gsum + slot * 16 + ((b ^ (slot & 3)) << 2)) = o;
            }
        }
        __syncthreads();   // A: gate sums visible

        // ---- activations on threads 0..255 (cell = tid) ----
        if (tid < 256) {
            const int cc = tid, sl = cc & 63, chi = cc >> 6;
            // gate g row = g*256+cc -> slot=cc&63, i=4g+chi -> block b=g, elem chi
            float s_i = gsum[sl * 16 + ((0 ^ (sl & 3)) << 2) + chi] + prg0;
            float s_f = gsum[sl * 16 + ((1 ^ (sl & 3)) << 2) + chi] + prg1;
            float s_g = gsum[sl * 16 + ((2 ^ (sl & 3)) << 2) + chi] + prg2;
            float s_o = gsum[sl * 16 + ((3 ^ (sl & 3)) << 2) + chi] + prg3;
            float i_ = fast_sigmoid(s_i);
            float f_ = fast_sigmoid(s_f);
            float g_ = fast_tanh(s_g);
            float o_ = fast_sigmoid(s_o);
            cst = f_ * cst + i_ * g_;
            float h = o_ * fast_tanh(cst);
            __fp16 hh = (__fp16)h;
            hbuf[cc] = hh;                          // next step's broadcast
            // history = the f16-rounded h actually used by the recurrence
            __builtin_nontemporal_store((float)hh, hs + (size_t)t * H2N + cc);
            // prefetch pre(t+1): lands during next step's dot phase
            if (t < SLEN - 1) {
                const float* pn = pre + (size_t)(t + 1) * G4 + cc;
                prg0 = pn[0];   prg1 = pn[256];
                prg2 = pn[512]; prg3 = pn[768];
            }
        }
        __syncthreads();   // B: h ready for next step
    }
}

// ---------------- K3: feats = concat(hs_f[s], hs_b[S-1-s]) @ w_out^T + b_out ----------------
__global__ __launch_bounds__(256) void feats_kernel(
    const float* __restrict__ hs_f, const float* __restrict__ hs_b,
    const float* __restrict__ w_out, const float* __restrict__ b_out,
    float* __restrict__ feats)
{
    const int rs0 = blockIdx.x * 16;
    const int tid = threadIdx.x;
    const int r = tid >> 4, cc = tid & 15;

    __shared__ float Hs[16][516];   // row stride 2064 B (16B-aligned)
    for (int i = tid; i < 16 * 256; i += 256) {
        int rr = i >> 8, k = i & 255;
        Hs[rr][k]       = hs_f[(size_t)(rs0 + rr) * H2N + k];
        Hs[rr][256 + k] = hs_b[(size_t)(SLEN - 1 - (rs0 + rr)) * H2N + k];
    }
    __syncthreads();

    float acc = 0.f;
    const float* wr = w_out + (size_t)cc * 512;
    const float* hrow = Hs[r];
#pragma unroll 4
    for (int kq = 0; kq < 128; kq++) {
        float4 hv = *(const float4*)(hrow + 4 * kq);
        float4 wv = *(const float4*)(wr + 4 * kq);
        acc += hv.x * wv.x; acc += hv.y * wv.y;
        acc += hv.z * wv.z; acc += hv.w * wv.w;
    }
    feats[(size_t)(rs0 + r) * NTAG + cc] = acc + b_out[cc];
}

// ---------------- K4: Viterbi scan + backtrack (single wave, LDS back-ptrs) ----------------
__global__ __launch_bounds__(64) void viterbi_kernel(
    const float* __restrict__ feats, const float* __restrict__ trans,
    float* __restrict__ out)
{
    __shared__ unsigned char back_s[SLEN * 8];   // 65536 B, [t][tag/2] nibbles

    const int lane = threadIdx.x;
    const int nx = lane >> 2, pc = lane & 3;   // next tag, prev-chunk

    float tr[4];
#pragma unroll
    for (int j = 0; j < 4; j++) tr[j] = trans[nx * NTAG + pc * 4 + j];

    // score of tag g lives (replicated) in lanes 4g..4g+3
    float sc = (nx == 0) ? 0.f : NEGV;
    float fe = feats[nx];   // prefetch t=0

    for (int t = 0; t < SLEN; t++) {
        float fe_next = (t < SLEN - 1) ? feats[(size_t)(t + 1) * NTAG + nx] : 0.f;

        float bv; int bi;
#pragma unroll
        for (int j = 0; j < 4; j++) {
            float s = __shfl(sc, 4 * (pc * 4 + j), 64);
            float cand = s + tr[j];
            if (j == 0) { bv = cand; bi = pc * 4; }
            else if (cand > bv) { bv = cand; bi = pc * 4 + j; }
        }
        // combine across the 4 prev-chunks; first-max semantics (tie -> smaller idx)
#pragma unroll
        for (int off = 1; off < 4; off <<= 1) {
            float ov = __shfl_xor(bv, off, 64);
            int   oi = __shfl_xor(bi, off, 64);
            if (ov > bv || (ov == bv && oi < bi)) { bv = ov; bi = oi; }
        }
        // nibble-pack: lane (nx even, pc==0) stores [bi(nx) | bi(nx+1)<<4]
        int bi_part = __shfl(bi, (nx | 1) * 4, 64);
        if (pc == 0 && (nx & 1) == 0)
            back_s[t * 8 + (nx >> 1)] = (unsigned char)((bi & 15) | (bi_part << 4));
        sc = bv + fe;
        fe = fe_next;
    }

    // final = last + trans[END=1]; first-argmax
    float bestv = 0.f; int besti = 0;
#pragma unroll
    for (int j = 0; j < NTAG; j++) {
        float sj = __shfl(sc, 4 * j, 64);
        float fj = sj + trans[1 * NTAG + j];
        if (j == 0) { bestv = fj; besti = 0; }
        else if (fj > bestv) { bestv = fj; besti = j; }
    }
    __syncthreads();

    if (lane == 0) {
        out[0] = bestv;
        int cur = besti;
        for (int t = SLEN - 1; t >= 1; t--) {
            out[1 + t] = (float)cur;
            unsigned char byte = back_s[t * 8 + (cur >> 1)];
            cur = (cur & 1) ? (byte >> 4) : (byte & 15);
        }
        out[1] = (float)cur;
    }
}

extern "C" void kernel_launch(void* const* d_in, const int* in_sizes, int n_in,
                              void* d_out, int out_size, void* d_ws, size_t ws_size,
                              hipStream_t stream) {
    const int*   sent   = (const int*)d_in[0];
    const float* emb    = (const float*)d_in[1];
    const float* w_ih_f = (const float*)d_in[2];
    const float* w_hh_f = (const float*)d_in[3];
    const float* b_f    = (const float*)d_in[4];
    const float* w_ih_b = (const float*)d_in[5];
    const float* w_hh_b = (const float*)d_in[6];
    const float* b_b    = (const float*)d_in[7];
    const float* h0_f   = (const float*)d_in[8];
    const float* c0_f   = (const float*)d_in[9];
    const float* h0_b   = (const float*)d_in[10];
    const float* c0_b   = (const float*)d_in[11];
    const float* w_out  = (const float*)d_in[12];
    const float* b_out  = (const float*)d_in[13];
    const float* trans  = (const float*)d_in[14];
    float* out = (float*)d_out;

    if (ws_size < WS_NEEDED) return;  // visible failure, no OOB writes

    float* ws = (float*)d_ws;
    float* pre_f = ws + OFF_PRE_F;
    float* pre_b = ws + OFF_PRE_B;
    float* hs_f  = ws + OFF_HS_F;
    float* hs_b  = ws + OFF_HS_B;
    float* feats = ws + OFF_FEATS;

    gemm_pre<<<dim3(128, 16, 2), 256, 0, stream>>>(sent, emb, w_ih_f, b_f, w_ih_b, b_b, pre_f, pre_b);
    lstm_kernel<<<2, 512, 0, stream>>>(pre_f, pre_b, w_hh_f, w_hh_b,
                                       h0_f, c0_f, h0_b, c0_b, hs_f, hs_b);
    feats_kernel<<<512, 256, 0, stream>>>(hs_f, hs_b, w_out, b_out, feats);
    viterbi_kernel<<<1, 64, 0, stream>>>(feats, trans, out);
}

// Round 9
// 18283.025 us; speedup vs baseline: 1.4365x; 1.0834x over previous
//
#include <hip/hip_runtime.h>
#include <math.h>

#define SLEN 8192
#define DIM  256
#define H2N  256
#define G4   1024
#define NTAG 16
#define NEGV (-10000.0f)

// ws layout (float offsets unless noted)
#define OFF_PRE_F   0
#define OFF_PRE_B   (SLEN*G4)
#define OFF_HS_F    (2*SLEN*G4)
#define OFF_HS_B    (2*SLEN*G4 + SLEN*H2N)
#define OFF_FEATS   (2*SLEN*G4 + 2*SLEN*H2N)
#define WS_NEEDED   ((size_t)(OFF_FEATS + SLEN*NTAG) * 4)

typedef unsigned int u32x4 __attribute__((ext_vector_type(4)));
typedef __fp16 h2_t __attribute__((ext_vector_type(2)));

__device__ __forceinline__ unsigned pack2(float x, float y) {
#if __has_builtin(__builtin_amdgcn_cvt_pkrtz)
    return __builtin_bit_cast(unsigned, __builtin_amdgcn_cvt_pkrtz(x, y));
#else
    union { __fp16 h[2]; unsigned u; } t;
    t.h[0] = (__fp16)x; t.h[1] = (__fp16)y;
    return t.u;
#endif
}

#if __has_builtin(__builtin_amdgcn_fdot2)
__device__ __forceinline__ float fdot2(unsigned a, unsigned b, float c) {
    return __builtin_amdgcn_fdot2(__builtin_bit_cast(h2_t, a),
                                  __builtin_bit_cast(h2_t, b), c, false);
}
#else
__device__ __forceinline__ float fdot2(unsigned a, unsigned b, float c) {
    union { unsigned u; __fp16 h[2]; } ua, ub;
    ua.u = a; ub.u = b;
    return c + (float)ua.h[0] * (float)ub.h[0] + (float)ua.h[1] * (float)ub.h[1];
}
#endif

// in-register reduce over the 8 k-group lanes (lane bits 0..2). All three
// DPP patterns are SYMMETRIC (involutions); verified end-to-end by R8's
// absmax=5.0 pass (f16-rounding class — a reduction bug would be O(100+)):
//   0xB1 = quad_perm[1,0,3,2]  (lane ^ 1)
//   0x4E = quad_perm[2,3,0,1]  (lane ^ 2)
//   0x141 = ROW_HALF_MIRROR    (lane ^ 7 within each 8-lane half-row)
template <int CTRL>
__device__ __forceinline__ float dpp_add(float x) {
    int v = __builtin_amdgcn_update_dpp(0, __float_as_int(x), CTRL, 0xF, 0xF, true);
    return x + __int_as_float(v);
}

// ---------------- K1: pre = gather(emb, sentence[±]) @ w_ih^T + b ----------------
__global__ __launch_bounds__(256) void gemm_pre(
    const int* __restrict__ sent, const float* __restrict__ emb,
    const float* __restrict__ wf, const float* __restrict__ bf,
    const float* __restrict__ wb, const float* __restrict__ bb,
    float* __restrict__ pre_f, float* __restrict__ pre_b)
{
    const int dir = blockIdx.z;
    const float* w    = dir ? wb : wf;
    const float* bias = dir ? bb : bf;
    float* out        = dir ? pre_b : pre_f;
    const int m0 = blockIdx.x * 64, n0 = blockIdx.y * 64;

    __shared__ float As[16][68];   // [k][m], row stride 272 B (16B-aligned)
    __shared__ float Bs[16][68];   // [k][n]
    __shared__ int   sidx[64];

    const int tid = threadIdx.x;
    const int tx = tid & 15, ty = tid >> 4;

    if (tid < 64) {
        int m = m0 + tid;
        int pos = dir ? (SLEN - 1 - m) : m;
        sidx[tid] = sent[pos];
    }
    __syncthreads();

    float acc[4][4];
#pragma unroll
    for (int i = 0; i < 4; i++)
#pragma unroll
        for (int j = 0; j < 4; j++) acc[i][j] = 0.f;

    const int lr = tid >> 2, lc = (tid & 3) * 4;

    for (int k0 = 0; k0 < DIM; k0 += 16) {
        float4 av = *(const float4*)(emb + (size_t)sidx[lr] * DIM + k0 + lc);
        float4 bv = *(const float4*)(w + (size_t)(n0 + lr) * DIM + k0 + lc);
        As[lc+0][lr] = av.x; As[lc+1][lr] = av.y; As[lc+2][lr] = av.z; As[lc+3][lr] = av.w;
        Bs[lc+0][lr] = bv.x; Bs[lc+1][lr] = bv.y; Bs[lc+2][lr] = bv.z; Bs[lc+3][lr] = bv.w;
        __syncthreads();
#pragma unroll
        for (int k = 0; k < 16; k++) {
            float4 a4 = *(const float4*)&As[k][ty * 4];
            float4 b4 = *(const float4*)&Bs[k][tx * 4];
            float a[4] = {a4.x, a4.y, a4.z, a4.w};
            float b[4] = {b4.x, b4.y, b4.z, b4.w};
#pragma unroll
            for (int i = 0; i < 4; i++)
#pragma unroll
                for (int j = 0; j < 4; j++) acc[i][j] += a[i] * b[j];
        }
        __syncthreads();
    }

    float4 b4 = *(const float4*)(bias + n0 + tx*4);
#pragma unroll
    for (int i = 0; i < 4; i++) {
        float4 v;
        v.x = acc[i][0] + b4.x; v.y = acc[i][1] + b4.y;
        v.z = acc[i][2] + b4.z; v.w = acc[i][3] + b4.w;
        *(float4*)(out + (size_t)(m0 + ty*4 + i) * G4 + n0 + tx*4) = v;
    }
}

__device__ __forceinline__ float fast_sigmoid(float x) {
    return 1.f / (1.f + __expf(-x));
}
__device__ __forceinline__ float fast_tanh(float x) {
    float xc = fminf(fmaxf(x, -15.f), 15.f);
    float e = __expf(2.f * xc);
    return (e - 1.f) / (e + 1.f);
}

// ---------------- K2: ONE CU per direction — zero cross-block exchange ----------------
// R16 (= R15 + register-budget fix): R8's counters showed VGPR_Count=128 —
// without the 2nd launch_bounds arg the compiler targeted 128 VGPRs (for
// occupancy this kernel can't have anyway: LDS=133KB -> 1 block/CU) and
// SPILLED the 192-reg W array to scratch. Scratch re-reads (~480B/thr/step,
// L2-resident -> low FETCH) ≈ 3800cy/step = the measured 4900cy period.
// Fixes:
//  (a) __launch_bounds__(512, 2): 2 waves/EU = 8 waves/CU (= this kernel's
//      actual residency) -> VGPR cap 256 (m69: waves halve at 64/128/256).
//      wreg 192 + hreg 16 + misc ~40 fits -> no spill.
//  (b) gsum relayout [gate*256+cell]: producer kg0 lane writes 4 scalar
//      ds_write_b32 at b*256+slot+64*ii (banks=slot%32, 8 lanes -> 8 distinct
//      banks, conflict-free); act read gsum[g*256+cc] is lane-consecutive,
//      conflict-free. R8's 5.77M bank-conflict cycles (~700cy/step) -> ~0.
// Design unchanged (verified by R8's absmax=5.0 pass): W f16 = 384KB VGPR
// (rows 0..11) + 128KB LDS (rows 12..15); per row 16 fdot2 + 3 symmetric
// DPP adds; act threads<256: gates+pre, fp32 c-state, h->f16 hbuf + NT
// history; pre(t+1) prefetched.
__global__ __launch_bounds__(512, 2) void lstm_kernel(
    const float* __restrict__ pre_f, const float* __restrict__ pre_b,
    const float* __restrict__ whh_f, const float* __restrict__ whh_b,
    const float* __restrict__ h0_f, const float* __restrict__ c0_f,
    const float* __restrict__ h0_b, const float* __restrict__ c0_b,
    float* __restrict__ hs_f, float* __restrict__ hs_b)
{
    const int d = blockIdx.x;            // 0..1: direction
    const float* pre = d ? pre_b : pre_f;
    const float* whh = d ? whh_b : whh_f;
    const float* h0  = d ? h0_b : h0_f;
    const float* c0  = d ? c0_b : c0_f;
    float* hs        = d ? hs_b : hs_f;

    const int tid = threadIdx.x;         // 0..511
    const int l   = tid & 63;
    const int w   = tid >> 6;            // wave 0..7
    const int kg  = l & 7;               // k-group (32 ks)
    const int rl  = l >> 3;              // row-lane 0..7
    const int slot = w * 8 + rl;         // 0..63
    const int k0 = kg * 32;

    __shared__ __align__(16) u32x4  wlds[16][512];  // 128 KB: rows 12..15
    __shared__ __align__(16) __fp16 hbuf[256];      // 512 B broadcast h
    __shared__ __align__(16) float  gsum[1024];     // 4 KB, [gate*256 + cell]

    // ---- stage W -> f16: rows 0..11 to VGPRs, 12..15 to LDS ----
    unsigned wreg[12][16];
#pragma unroll
    for (int i = 0; i < 16; i++) {
        const float* wsrc = whh + (size_t)(slot + 64 * i) * H2N + k0;
        unsigned pk[16];
#pragma unroll
        for (int q = 0; q < 8; q++) {
            float4 v = *(const float4*)(wsrc + 4 * q);
            pk[2 * q]     = pack2(v.x, v.y);
            pk[2 * q + 1] = pack2(v.z, v.w);
        }
        if (i < 12) {
#pragma unroll
            for (int p = 0; p < 16; p++) wreg[i][p] = pk[p];
        } else {
#pragma unroll
            for (int c4 = 0; c4 < 4; c4++) {
                u32x4 vv;
                vv.x = pk[4*c4+0]; vv.y = pk[4*c4+1];
                vv.z = pk[4*c4+2]; vv.w = pk[4*c4+3];
                wlds[(i - 12) * 4 + c4][tid] = vv;
            }
        }
    }

    // ---- init: h0 -> f16 broadcast buffer, c-state + pre(0) in act regs ----
    float cst = 0.f, prg0 = 0.f, prg1 = 0.f, prg2 = 0.f, prg3 = 0.f;
    if (tid < 256) {
        hbuf[tid] = (__fp16)h0[tid];
        cst  = c0[tid];
        prg0 = pre[0 * 256 + tid];
        prg1 = pre[1 * 256 + tid];
        prg2 = pre[2 * 256 + tid];
        prg3 = pre[3 * 256 + tid];
    }
    __syncthreads();

    for (int t = 0; t < SLEN; t++) {
        // ---- load h (broadcast, packed f16 pairs) into regs ----
        unsigned hreg[16];
        {
            const u32x4* hp = (const u32x4*)((const char*)hbuf + kg * 64);
#pragma unroll
            for (int j = 0; j < 4; j++) {
                u32x4 hv = hp[j];
                hreg[4*j+0] = hv.x; hreg[4*j+1] = hv.y;
                hreg[4*j+2] = hv.z; hreg[4*j+3] = hv.w;
            }
        }

        // ---- 16 gate-row partial dots + DPP reduce + gsum scatter ----
#pragma unroll
        for (int b = 0; b < 4; b++) {
            float sv[4];
#pragma unroll
            for (int ii = 0; ii < 4; ii++) {
                const int i = 4 * b + ii;
                float a0 = 0.f, a1 = 0.f;
                if (i < 12) {
#pragma unroll
                    for (int p = 0; p < 16; p += 2) {
                        a0 = fdot2(wreg[i][p],     hreg[p],     a0);
                        a1 = fdot2(wreg[i][p + 1], hreg[p + 1], a1);
                    }
                } else {
#pragma unroll
                    for (int c4 = 0; c4 < 4; c4++) {
                        u32x4 wc = wlds[(i - 12) * 4 + c4][tid];
                        a0 = fdot2(wc.x, hreg[4*c4+0], a0);
                        a1 = fdot2(wc.y, hreg[4*c4+1], a1);
                        a0 = fdot2(wc.z, hreg[4*c4+2], a0);
                        a1 = fdot2(wc.w, hreg[4*c4+3], a1);
                    }
                }
                float a = a0 + a1;
                a = dpp_add<0xB1>(a);    // + (kg^1)
                a = dpp_add<0x4E>(a);    // + (kg^2)
                a = dpp_add<0x141>(a);   // + (kg^7): other quad (half-mirror)
                sv[ii] = a;
            }
            if (kg == 0) {
                // gate b, cells slot+64*ii: banks = slot%32 -> the 8 kg0
                // lanes of a wave hit 8 distinct banks (conflict-free)
                gsum[b * 256 + slot +   0] = sv[0];
                gsum[b * 256 + slot +  64] = sv[1];
                gsum[b * 256 + slot + 128] = sv[2];
                gsum[b * 256 + slot + 192] = sv[3];
            }
        }
        __syncthreads();   // A: gate sums visible

        // ---- activations on threads 0..255 (cell = tid) ----
        if (tid < 256) {
            const int cc = tid;
            // lane-consecutive reads: conflict-free
            float s_i = gsum[  0 + cc] + prg0;
            float s_f = gsum[256 + cc] + prg1;
            float s_g = gsum[512 + cc] + prg2;
            float s_o = gsum[768 + cc] + prg3;
            float i_ = fast_sigmoid(s_i);
            float f_ = fast_sigmoid(s_f);
            float g_ = fast_tanh(s_g);
            float o_ = fast_sigmoid(s_o);
            cst = f_ * cst + i_ * g_;
            float h = o_ * fast_tanh(cst);
            __fp16 hh = (__fp16)h;
            hbuf[cc] = hh;                          // next step's broadcast
            // history = the f16-rounded h actually used by the recurrence
            __builtin_nontemporal_store((float)hh, hs + (size_t)t * H2N + cc);
            // prefetch pre(t+1): lands during next step's dot phase
            if (t < SLEN - 1) {
                const float* pn = pre + (size_t)(t + 1) * G4 + cc;
                prg0 = pn[0];   prg1 = pn[256];
                prg2 = pn[512]; prg3 = pn[768];
            }
        }
        __syncthreads();   // B: h ready for next step
    }
}

// ---------------- K3: feats = concat(hs_f[s], hs_b[S-1-s]) @ w_out^T + b_out ----------------
__global__ __launch_bounds__(256) void feats_kernel(
    const float* __restrict__ hs_f, const float* __restrict__ hs_b,
    const float* __restrict__ w_out, const float* __restrict__ b_out,
    float* __restrict__ feats)
{
    const int rs0 = blockIdx.x * 16;
    const int tid = threadIdx.x;
    const int r = tid >> 4, cc = tid & 15;

    __shared__ float Hs[16][516];   // row stride 2064 B (16B-aligned)
    for (int i = tid; i < 16 * 256; i += 256) {
        int rr = i >> 8, k = i & 255;
        Hs[rr][k]       = hs_f[(size_t)(rs0 + rr) * H2N + k];
        Hs[rr][256 + k] = hs_b[(size_t)(SLEN - 1 - (rs0 + rr)) * H2N + k];
    }
    __syncthreads();

    float acc = 0.f;
    const float* wr = w_out + (size_t)cc * 512;
    const float* hrow = Hs[r];
#pragma unroll 4
    for (int kq = 0; kq < 128; kq++) {
        float4 hv = *(const float4*)(hrow + 4 * kq);
        float4 wv = *(const float4*)(wr + 4 * kq);
        acc += hv.x * wv.x; acc += hv.y * wv.y;
        acc += hv.z * wv.z; acc += hv.w * wv.w;
    }
    feats[(size_t)(rs0 + r) * NTAG + cc] = acc + b_out[cc];
}

// ---------------- K4: Viterbi scan + backtrack (single wave, LDS back-ptrs) ----------------
__global__ __launch_bounds__(64) void viterbi_kernel(
    const float* __restrict__ feats, const float* __restrict__ trans,
    float* __restrict__ out)
{
    __shared__ unsigned char back_s[SLEN * 8];   // 65536 B, [t][tag/2] nibbles

    const int lane = threadIdx.x;
    const int nx = lane >> 2, pc = lane & 3;   // next tag, prev-chunk

    float tr[4];
#pragma unroll
    for (int j = 0; j < 4; j++) tr[j] = trans[nx * NTAG + pc * 4 + j];

    // score of tag g lives (replicated) in lanes 4g..4g+3
    float sc = (nx == 0) ? 0.f : NEGV;
    float fe = feats[nx];   // prefetch t=0

    for (int t = 0; t < SLEN; t++) {
        float fe_next = (t < SLEN - 1) ? feats[(size_t)(t + 1) * NTAG + nx] : 0.f;

        float bv; int bi;
#pragma unroll
        for (int j = 0; j < 4; j++) {
            float s = __shfl(sc, 4 * (pc * 4 + j), 64);
            float cand = s + tr[j];
            if (j == 0) { bv = cand; bi = pc * 4; }
            else if (cand > bv) { bv = cand; bi = pc * 4 + j; }
        }
        // combine across the 4 prev-chunks; first-max semantics (tie -> smaller idx)
#pragma unroll
        for (int off = 1; off < 4; off <<= 1) {
            float ov = __shfl_xor(bv, off, 64);
            int   oi = __shfl_xor(bi, off, 64);
            if (ov > bv || (ov == bv && oi < bi)) { bv = ov; bi = oi; }
        }
        // nibble-pack: lane (nx even, pc==0) stores [bi(nx) | bi(nx+1)<<4]
        int bi_part = __shfl(bi, (nx | 1) * 4, 64);
        if (pc == 0 && (nx & 1) == 0)
            back_s[t * 8 + (nx >> 1)] = (unsigned char)((bi & 15) | (bi_part << 4));
        sc = bv + fe;
        fe = fe_next;
    }

    // final = last + trans[END=1]; first-argmax
    float bestv = 0.f; int besti = 0;
#pragma unroll
    for (int j = 0; j < NTAG; j++) {
        float sj = __shfl(sc, 4 * j, 64);
        float fj = sj + trans[1 * NTAG + j];
        if (j == 0) { bestv = fj; besti = 0; }
        else if (fj > bestv) { bestv = fj; besti = j; }
    }
    __syncthreads();

    if (lane == 0) {
        out[0] = bestv;
        int cur = besti;
        for (int t = SLEN - 1; t >= 1; t--) {
            out[1 + t] = (float)cur;
            unsigned char byte = back_s[t * 8 + (cur >> 1)];
            cur = (cur & 1) ? (byte >> 4) : (byte & 15);
        }
        out[1] = (float)cur;
    }
}

extern "C" void kernel_launch(void* const* d_in, const int* in_sizes, int n_in,
                              void* d_out, int out_size, void* d_ws, size_t ws_size,
                              hipStream_t stream) {
    const int*   sent   = (const int*)d_in[0];
    const float* emb    = (const float*)d_in[1];
    const float* w_ih_f = (const float*)d_in[2];
    const float* w_hh_f = (const float*)d_in[3];
    const float* b_f    = (const float*)d_in[4];
    const float* w_ih_b = (const float*)d_in[5];
    const float* w_hh_b = (const float*)d_in[6];
    const float* b_b    = (const float*)d_in[7];
    const float* h0_f   = (const float*)d_in[8];
    const float* c0_f   = (const float*)d_in[9];
    const float* h0_b   = (const float*)d_in[10];
    const float* c0_b   = (const float*)d_in[11];
    const float* w_out  = (const float*)d_in[12];
    const float* b_out  = (const float*)d_in[13];
    const float* trans  = (const float*)d_in[14];
    float* out = (float*)d_out;

    if (ws_size < WS_NEEDED) return;  // visible failure, no OOB writes

    float* ws = (float*)d_ws;
    float* pre_f = ws + OFF_PRE_F;
    float* pre_b = ws + OFF_PRE_B;
    float* hs_f  = ws + OFF_HS_F;
    float* hs_b  = ws + OFF_HS_B;
    float* feats = ws + OFF_FEATS;

    gemm_pre<<<dim3(128, 16, 2), 256, 0, stream>>>(sent, emb, w_ih_f, b_f, w_ih_b, b_b, pre_f, pre_b);
    lstm_kernel<<<2, 512, 0, stream>>>(pre_f, pre_b, w_hh_f, w_hh_b,
                                       h0_f, c0_f, h0_b, c0_b, hs_f, hs_b);
    feats_kernel<<<512, 256, 0, stream>>>(hs_f, hs_b, w_out, b_out, feats);
    viterbi_kernel<<<1, 64, 0, stream>>>(feats, trans, out);
}

// Round 10
// 17875.975 us; speedup vs baseline: 1.4692x; 1.0228x over previous
//
#include <hip/hip_runtime.h>
#include <math.h>

#define SLEN 8192
#define DIM  256
#define H2N  256
#define G4   1024
#define NTAG 16
#define NEGV (-10000.0f)

// ws layout (float offsets unless noted)
#define OFF_PRE_F   0
#define OFF_PRE_B   (SLEN*G4)
#define OFF_HS_F    (2*SLEN*G4)
#define OFF_HS_B    (2*SLEN*G4 + SLEN*H2N)
#define OFF_FEATS   (2*SLEN*G4 + 2*SLEN*H2N)
#define WS_NEEDED   ((size_t)(OFF_FEATS + SLEN*NTAG) * 4)

typedef unsigned int u32x4 __attribute__((ext_vector_type(4)));
typedef __fp16 h2_t __attribute__((ext_vector_type(2)));

__device__ __forceinline__ unsigned pack2(float x, float y) {
#if __has_builtin(__builtin_amdgcn_cvt_pkrtz)
    return __builtin_bit_cast(unsigned, __builtin_amdgcn_cvt_pkrtz(x, y));
#else
    union { __fp16 h[2]; unsigned u; } t;
    t.h[0] = (__fp16)x; t.h[1] = (__fp16)y;
    return t.u;
#endif
}

#if __has_builtin(__builtin_amdgcn_fdot2)
__device__ __forceinline__ float fdot2(unsigned a, unsigned b, float c) {
    return __builtin_amdgcn_fdot2(__builtin_bit_cast(h2_t, a),
                                  __builtin_bit_cast(h2_t, b), c, false);
}
#else
__device__ __forceinline__ float fdot2(unsigned a, unsigned b, float c) {
    union { unsigned u; __fp16 h[2]; } ua, ub;
    ua.u = a; ub.u = b;
    return c + (float)ua.h[0] * (float)ub.h[0] + (float)ua.h[1] * (float)ub.h[1];
}
#endif

// in-register reduce over the 8 k-group lanes (lane bits 0..2). All three
// DPP patterns are SYMMETRIC (involutions); verified end-to-end by R8/R9's
// absmax=5.0 passes (f16-rounding class — a reduction bug would be O(100+)):
//   0xB1 = quad_perm[1,0,3,2]  (lane ^ 1)
//   0x4E = quad_perm[2,3,0,1]  (lane ^ 2)
//   0x141 = ROW_HALF_MIRROR    (lane ^ 7 within each 8-lane half-row)
template <int CTRL>
__device__ __forceinline__ float dpp_add(float x) {
    int v = __builtin_amdgcn_update_dpp(0, __float_as_int(x), CTRL, 0xF, 0xF, true);
    return x + __int_as_float(v);
}

// ---------------- K1: pre = gather(emb, sentence[±]) @ w_ih^T + b ----------------
__global__ __launch_bounds__(256) void gemm_pre(
    const int* __restrict__ sent, const float* __restrict__ emb,
    const float* __restrict__ wf, const float* __restrict__ bf,
    const float* __restrict__ wb, const float* __restrict__ bb,
    float* __restrict__ pre_f, float* __restrict__ pre_b)
{
    const int dir = blockIdx.z;
    const float* w    = dir ? wb : wf;
    const float* bias = dir ? bb : bf;
    float* out        = dir ? pre_b : pre_f;
    const int m0 = blockIdx.x * 64, n0 = blockIdx.y * 64;

    __shared__ float As[16][68];   // [k][m], row stride 272 B (16B-aligned)
    __shared__ float Bs[16][68];   // [k][n]
    __shared__ int   sidx[64];

    const int tid = threadIdx.x;
    const int tx = tid & 15, ty = tid >> 4;

    if (tid < 64) {
        int m = m0 + tid;
        int pos = dir ? (SLEN - 1 - m) : m;
        sidx[tid] = sent[pos];
    }
    __syncthreads();

    float acc[4][4];
#pragma unroll
    for (int i = 0; i < 4; i++)
#pragma unroll
        for (int j = 0; j < 4; j++) acc[i][j] = 0.f;

    const int lr = tid >> 2, lc = (tid & 3) * 4;

    for (int k0 = 0; k0 < DIM; k0 += 16) {
        float4 av = *(const float4*)(emb + (size_t)sidx[lr] * DIM + k0 + lc);
        float4 bv = *(const float4*)(w + (size_t)(n0 + lr) * DIM + k0 + lc);
        As[lc+0][lr] = av.x; As[lc+1][lr] = av.y; As[lc+2][lr] = av.z; As[lc+3][lr] = av.w;
        Bs[lc+0][lr] = bv.x; Bs[lc+1][lr] = bv.y; Bs[lc+2][lr] = bv.z; Bs[lc+3][lr] = bv.w;
        __syncthreads();
#pragma unroll
        for (int k = 0; k < 16; k++) {
            float4 a4 = *(const float4*)&As[k][ty * 4];
            float4 b4 = *(const float4*)&Bs[k][tx * 4];
            float a[4] = {a4.x, a4.y, a4.z, a4.w};
            float b[4] = {b4.x, b4.y, b4.z, b4.w};
#pragma unroll
            for (int i = 0; i < 4; i++)
#pragma unroll
                for (int j = 0; j < 4; j++) acc[i][j] += a[i] * b[j];
        }
        __syncthreads();
    }

    float4 b4 = *(const float4*)(bias + n0 + tx*4);
#pragma unroll
    for (int i = 0; i < 4; i++) {
        float4 v;
        v.x = acc[i][0] + b4.x; v.y = acc[i][1] + b4.y;
        v.z = acc[i][2] + b4.z; v.w = acc[i][3] + b4.w;
        *(float4*)(out + (size_t)(m0 + ty*4 + i) * G4 + n0 + tx*4) = v;
    }
}

__device__ __forceinline__ float fast_sigmoid(float x) {
    return 1.f / (1.f + __expf(-x));
}
__device__ __forceinline__ float fast_tanh(float x) {
    float xc = fminf(fmaxf(x, -15.f), 15.f);
    float e = __expf(2.f * xc);
    return (e - 1.f) / (e + 1.f);
}

// ---------------- K2: ONE CU per direction — zero cross-block exchange ----------------
// R17 (= R16 + the two counter-diagnosed fixes):
//  (a) R9 showed VGPR_Count STILL 128: this toolchain reads launch_bounds'
//      2nd arg as min BLOCKS/CU (CUDA semantics): (512,2) -> 2 blk x 8 waves
//      / 4 SIMD = 4 waves/EU -> cap 128 -> the 192-reg W array spilled to
//      scratch (~2000+cy/step). Fix: __launch_bounds__(512, 1): blocks-
//      interp -> 8 waves/CU = 2 waves/EU -> cap 256; waves-interp -> min 1,
//      but flat-workgroup 512 (8 co-resident waves) still clamps to 256.
//      Either semantics -> cap 256; wreg 192 + hreg 16 + misc ~30 fits.
//  (b) R9's residual 2.1M LDS bank conflicts = hbuf broadcast reads:
//      addr kg*64+j*16 puts kg{0,2,4,6} on the same dword-banks (4-way).
//      Fix: pad region stride to 80B (16B-aligned): banks (kg*20+j*4)%32 =
//      {0,20,8,28,16,4,24,12} -- all distinct, conflict-free.
// Design unchanged (verified absmax=5.0 in R8/R9): W f16 = 384KB VGPR
// (rows 0..11) + 128KB LDS (rows 12..15); per row 16 fdot2 + 3 symmetric
// DPP adds; act threads<256: gates+pre, fp32 c-state, h->f16 hbuf + NT
// history; pre(t+1) prefetched. gsum [gate*256+cell] (R9, conflict-free).
__global__ __launch_bounds__(512, 1) void lstm_kernel(
    const float* __restrict__ pre_f, const float* __restrict__ pre_b,
    const float* __restrict__ whh_f, const float* __restrict__ whh_b,
    const float* __restrict__ h0_f, const float* __restrict__ c0_f,
    const float* __restrict__ h0_b, const float* __restrict__ c0_b,
    float* __restrict__ hs_f, float* __restrict__ hs_b)
{
    const int d = blockIdx.x;            // 0..1: direction
    const float* pre = d ? pre_b : pre_f;
    const float* whh = d ? whh_b : whh_f;
    const float* h0  = d ? h0_b : h0_f;
    const float* c0  = d ? c0_b : c0_f;
    float* hs        = d ? hs_b : hs_f;

    const int tid = threadIdx.x;         // 0..511
    const int l   = tid & 63;
    const int w   = tid >> 6;            // wave 0..7
    const int kg  = l & 7;               // k-group (32 ks)
    const int rl  = l >> 3;              // row-lane 0..7
    const int slot = w * 8 + rl;         // 0..63
    const int k0 = kg * 32;

    __shared__ __align__(16) u32x4  wlds[16][512];  // 128 KB: rows 12..15
    __shared__ __align__(16) __fp16 hbuf[8 * 40];   // 640 B: 8 regions x 80 B
    __shared__ __align__(16) float  gsum[1024];     // 4 KB, [gate*256 + cell]

    // ---- stage W -> f16: rows 0..11 to VGPRs, 12..15 to LDS ----
    unsigned wreg[12][16];
#pragma unroll
    for (int i = 0; i < 16; i++) {
        const float* wsrc = whh + (size_t)(slot + 64 * i) * H2N + k0;
        unsigned pk[16];
#pragma unroll
        for (int q = 0; q < 8; q++) {
            float4 v = *(const float4*)(wsrc + 4 * q);
            pk[2 * q]     = pack2(v.x, v.y);
            pk[2 * q + 1] = pack2(v.z, v.w);
        }
        if (i < 12) {
#pragma unroll
            for (int p = 0; p < 16; p++) wreg[i][p] = pk[p];
        } else {
#pragma unroll
            for (int c4 = 0; c4 < 4; c4++) {
                u32x4 vv;
                vv.x = pk[4*c4+0]; vv.y = pk[4*c4+1];
                vv.z = pk[4*c4+2]; vv.w = pk[4*c4+3];
                wlds[(i - 12) * 4 + c4][tid] = vv;
            }
        }
    }

    // ---- init: h0 -> f16 region buffer, c-state + pre(0) in act regs ----
    float cst = 0.f, prg0 = 0.f, prg1 = 0.f, prg2 = 0.f, prg3 = 0.f;
    if (tid < 256) {
        // half index tid -> region tid>>5 (80B stride), elem tid&31
        *(__fp16*)((char*)hbuf + (tid >> 5) * 80 + (tid & 31) * 2) = (__fp16)h0[tid];
        cst  = c0[tid];
        prg0 = pre[0 * 256 + tid];
        prg1 = pre[1 * 256 + tid];
        prg2 = pre[2 * 256 + tid];
        prg3 = pre[3 * 256 + tid];
    }
    __syncthreads();

    for (int t = 0; t < SLEN; t++) {
        // ---- load h (broadcast, packed f16 pairs) into regs ----
        unsigned hreg[16];
        {
            const u32x4* hp = (const u32x4*)((const char*)hbuf + kg * 80);
#pragma unroll
            for (int j = 0; j < 4; j++) {
                u32x4 hv = hp[j];
                hreg[4*j+0] = hv.x; hreg[4*j+1] = hv.y;
                hreg[4*j+2] = hv.z; hreg[4*j+3] = hv.w;
            }
        }

        // ---- 16 gate-row partial dots + DPP reduce + gsum scatter ----
#pragma unroll
        for (int b = 0; b < 4; b++) {
            float sv[4];
#pragma unroll
            for (int ii = 0; ii < 4; ii++) {
                const int i = 4 * b + ii;
                float a0 = 0.f, a1 = 0.f;
                if (i < 12) {
#pragma unroll
                    for (int p = 0; p < 16; p += 2) {
                        a0 = fdot2(wreg[i][p],     hreg[p],     a0);
                        a1 = fdot2(wreg[i][p + 1], hreg[p + 1], a1);
                    }
                } else {
#pragma unroll
                    for (int c4 = 0; c4 < 4; c4++) {
                        u32x4 wc = wlds[(i - 12) * 4 + c4][tid];
                        a0 = fdot2(wc.x, hreg[4*c4+0], a0);
                        a1 = fdot2(wc.y, hreg[4*c4+1], a1);
                        a0 = fdot2(wc.z, hreg[4*c4+2], a0);
                        a1 = fdot2(wc.w, hreg[4*c4+3], a1);
                    }
                }
                float a = a0 + a1;
                a = dpp_add<0xB1>(a);    // + (kg^1)
                a = dpp_add<0x4E>(a);    // + (kg^2)
                a = dpp_add<0x141>(a);   // + (kg^7): other quad (half-mirror)
                sv[ii] = a;
            }
            if (kg == 0) {
                // gate b, cells slot+64*ii: banks = slot%32 -> the 8 kg0
                // lanes of a wave hit 8 distinct banks (conflict-free)
                gsum[b * 256 + slot +   0] = sv[0];
                gsum[b * 256 + slot +  64] = sv[1];
                gsum[b * 256 + slot + 128] = sv[2];
                gsum[b * 256 + slot + 192] = sv[3];
            }
        }
        __syncthreads();   // A: gate sums visible

        // ---- activations on threads 0..255 (cell = tid) ----
        if (tid < 256) {
            const int cc = tid;
            // lane-consecutive reads: conflict-free
            float s_i = gsum[  0 + cc] + prg0;
            float s_f = gsum[256 + cc] + prg1;
            float s_g = gsum[512 + cc] + prg2;
            float s_o = gsum[768 + cc] + prg3;
            float i_ = fast_sigmoid(s_i);
            float f_ = fast_sigmoid(s_f);
            float g_ = fast_tanh(s_g);
            float o_ = fast_sigmoid(s_o);
            cst = f_ * cst + i_ * g_;
            float h = o_ * fast_tanh(cst);
            __fp16 hh = (__fp16)h;
            *(__fp16*)((char*)hbuf + (cc >> 5) * 80 + (cc & 31) * 2) = hh;
            // history = the f16-rounded h actually used by the recurrence
            __builtin_nontemporal_store((float)hh, hs + (size_t)t * H2N + cc);
            // prefetch pre(t+1): lands during next step's dot phase
            if (t < SLEN - 1) {
                const float* pn = pre + (size_t)(t + 1) * G4 + cc;
                prg0 = pn[0];   prg1 = pn[256];
                prg2 = pn[512]; prg3 = pn[768];
            }
        }
        __syncthreads();   // B: h ready for next step
    }
}

// ---------------- K3: feats = concat(hs_f[s], hs_b[S-1-s]) @ w_out^T + b_out ----------------
__global__ __launch_bounds__(256) void feats_kernel(
    const float* __restrict__ hs_f, const float* __restrict__ hs_b,
    const float* __restrict__ w_out, const float* __restrict__ b_out,
    float* __restrict__ feats)
{
    const int rs0 = blockIdx.x * 16;
    const int tid = threadIdx.x;
    const int r = tid >> 4, cc = tid & 15;

    __shared__ float Hs[16][516];   // row stride 2064 B (16B-aligned)
    for (int i = tid; i < 16 * 256; i += 256) {
        int rr = i >> 8, k = i & 255;
        Hs[rr][k]       = hs_f[(size_t)(rs0 + rr) * H2N + k];
        Hs[rr][256 + k] = hs_b[(size_t)(SLEN - 1 - (rs0 + rr)) * H2N + k];
    }
    __syncthreads();

    float acc = 0.f;
    const float* wr = w_out + (size_t)cc * 512;
    const float* hrow = Hs[r];
#pragma unroll 4
    for (int kq = 0; kq < 128; kq++) {
        float4 hv = *(const float4*)(hrow + 4 * kq);
        float4 wv = *(const float4*)(wr + 4 * kq);
        acc += hv.x * wv.x; acc += hv.y * wv.y;
        acc += hv.z * wv.z; acc += hv.w * wv.w;
    }
    feats[(size_t)(rs0 + r) * NTAG + cc] = acc + b_out[cc];
}

// ---------------- K4: Viterbi scan + backtrack (single wave, LDS back-ptrs) ----------------
__global__ __launch_bounds__(64) void viterbi_kernel(
    const float* __restrict__ feats, const float* __restrict__ trans,
    float* __restrict__ out)
{
    __shared__ unsigned char back_s[SLEN * 8];   // 65536 B, [t][tag/2] nibbles

    const int lane = threadIdx.x;
    const int nx = lane >> 2, pc = lane & 3;   // next tag, prev-chunk

    float tr[4];
#pragma unroll
    for (int j = 0; j < 4; j++) tr[j] = trans[nx * NTAG + pc * 4 + j];

    // score of tag g lives (replicated) in lanes 4g..4g+3
    float sc = (nx == 0) ? 0.f : NEGV;
    float fe = feats[nx];   // prefetch t=0

    for (int t = 0; t < SLEN; t++) {
        float fe_next = (t < SLEN - 1) ? feats[(size_t)(t + 1) * NTAG + nx] : 0.f;

        float bv; int bi;
#pragma unroll
        for (int j = 0; j < 4; j++) {
            float s = __shfl(sc, 4 * (pc * 4 + j), 64);
            float cand = s + tr[j];
            if (j == 0) { bv = cand; bi = pc * 4; }
            else if (cand > bv) { bv = cand; bi = pc * 4 + j; }
        }
        // combine across the 4 prev-chunks; first-max semantics (tie -> smaller idx)
#pragma unroll
        for (int off = 1; off < 4; off <<= 1) {
            float ov = __shfl_xor(bv, off, 64);
            int   oi = __shfl_xor(bi, off, 64);
            if (ov > bv || (ov == bv && oi < bi)) { bv = ov; bi = oi; }
        }
        // nibble-pack: lane (nx even, pc==0) stores [bi(nx) | bi(nx+1)<<4]
        int bi_part = __shfl(bi, (nx | 1) * 4, 64);
        if (pc == 0 && (nx & 1) == 0)
            back_s[t * 8 + (nx >> 1)] = (unsigned char)((bi & 15) | (bi_part << 4));
        sc = bv + fe;
        fe = fe_next;
    }

    // final = last + trans[END=1]; first-argmax
    float bestv = 0.f; int besti = 0;
#pragma unroll
    for (int j = 0; j < NTAG; j++) {
        float sj = __shfl(sc, 4 * j, 64);
        float fj = sj + trans[1 * NTAG + j];
        if (j == 0) { bestv = fj; besti = 0; }
        else if (fj > bestv) { bestv = fj; besti = j; }
    }
    __syncthreads();

    if (lane == 0) {
        out[0] = bestv;
        int cur = besti;
        for (int t = SLEN - 1; t >= 1; t--) {
            out[1 + t] = (float)cur;
            unsigned char byte = back_s[t * 8 + (cur >> 1)];
            cur = (cur & 1) ? (byte >> 4) : (byte & 15);
        }
        out[1] = (float)cur;
    }
}

extern "C" void kernel_launch(void* const* d_in, const int* in_sizes, int n_in,
                              void* d_out, int out_size, void* d_ws, size_t ws_size,
                              hipStream_t stream) {
    const int*   sent   = (const int*)d_in[0];
    const float* emb    = (const float*)d_in[1];
    const float* w_ih_f = (const float*)d_in[2];
    const float* w_hh_f = (const float*)d_in[3];
    const float* b_f    = (const float*)d_in[4];
    const float* w_ih_b = (const float*)d_in[5];
    const float* w_hh_b = (const float*)d_in[6];
    const float* b_b    = (const float*)d_in[7];
    const float* h0_f   = (const float*)d_in[8];
    const float* c0_f   = (const float*)d_in[9];
    const float* h0_b   = (const float*)d_in[10];
    const float* c0_b   = (const float*)d_in[11];
    const float* w_out  = (const float*)d_in[12];
    const float* b_out  = (const float*)d_in[13];
    const float* trans  = (const float*)d_in[14];
    float* out = (float*)d_out;

    if (ws_size < WS_NEEDED) return;  // visible failure, no OOB writes

    float* ws = (float*)d_ws;
    float* pre_f = ws + OFF_PRE_F;
    float* pre_b = ws + OFF_PRE_B;
    float* hs_f  = ws + OFF_HS_F;
    float* hs_b  = ws + OFF_HS_B;
    float* feats = ws + OFF_FEATS;

    gemm_pre<<<dim3(128, 16, 2), 256, 0, stream>>>(sent, emb, w_ih_f, b_f, w_ih_b, b_b, pre_f, pre_b);
    lstm_kernel<<<2, 512, 0, stream>>>(pre_f, pre_b, w_hh_f, w_hh_b,
                                       h0_f, c0_f, h0_b, c0_b, hs_f, hs_b);
    feats_kernel<<<512, 256, 0, stream>>>(hs_f, hs_b, w_out, b_out, feats);
    viterbi_kernel<<<1, 64, 0, stream>>>(feats, trans, out);
}